// Round 1
// baseline (325.270 us; speedup 1.0000x reference)
//
#include <hip/hip_runtime.h>

#define BATCH 32
#define DZ    8192
#define LG    576
#define LL    256
#define CH    512

// ---- ws layout (byte offsets) ----
#define OFF_ACC   0                       // double[16] accumulators
#define OFF_MA    128                     // float[DZ] mean of z_global per feature
#define OFF_MB    (OFF_MA + 4*DZ)         // float[DZ] mean of z_local
#define OFF_NG    (OFF_MB + 4*DZ)         // float[BATCH*LG] |zg row|^2
#define OFF_NL    (OFF_NG + 4*BATCH*LG)   // float[BATCH*LL] |zl row|^2
#define OFF_ROWNN (OFF_NL + 4*BATCH*LL)   // u64[BATCH*LG] packed (d2,idx) NN g->l
#define OFF_COLNN (OFF_ROWNN + 8*BATCH*LG)// u64[BATCH*LL] packed NN l->g
// total = 385152 bytes

// acc indices: 0 inv_global, 1 var_a, 2 var_b, 3 diag_a, 4 diag_b,
//              5 G2_a, 6 G2_b, 7 feat_g, 8 feat_l, 9 grid_g, 10 grid_l

__device__ __forceinline__ float blk_reduce(float v, float* s) {
  int t = threadIdx.x;
  s[t] = v; __syncthreads();
  for (int off = 128; off > 0; off >>= 1) {
    if (t < off) s[t] += s[t + off];
    __syncthreads();
  }
  float r = s[0]; __syncthreads();
  return r;
}

// -------- global VICReg stats: per-feature mean/var + inv mse + diag(cov)^2 --------
__global__ __launch_bounds__(256) void k_global_stats(
    const float* __restrict__ za, const float* __restrict__ zb,
    double* __restrict__ acc, float* __restrict__ ma, float* __restrict__ mb) {
  __shared__ float sred[256];
  int i = blockIdx.x * 256 + threadIdx.x;  // feature 0..8191
  float sa = 0.f, qa = 0.f, sb = 0.f, qb = 0.f, si = 0.f;
  for (int b = 0; b < BATCH; ++b) {
    float va = za[(size_t)b * DZ + i];
    float vb = zb[(size_t)b * DZ + i];
    sa += va; qa += va * va;
    sb += vb; qb += vb * vb;
    float d = va - vb; si += d * d;
  }
  ma[i] = sa * (1.f / 32.f);
  mb[i] = sb * (1.f / 32.f);
  float ssa = qa - sa * sa * (1.f / 32.f);  // centered sum of squares (= 31*var)
  float ssb = qb - sb * sb * (1.f / 32.f);
  float ra = fmaxf(0.f, 1.f - sqrtf(ssa * (1.f / 31.f) + 1e-4f));
  float rb = fmaxf(0.f, 1.f - sqrtf(ssb * (1.f / 31.f) + 1e-4f));
  float r;
  r = blk_reduce(si, sred);        if (threadIdx.x == 0) atomicAdd(&acc[0], (double)r);
  r = blk_reduce(ra, sred);        if (threadIdx.x == 0) atomicAdd(&acc[1], (double)r);
  r = blk_reduce(rb, sred);        if (threadIdx.x == 0) atomicAdd(&acc[2], (double)r);
  r = blk_reduce(ssa * ssa, sred); if (threadIdx.x == 0) atomicAdd(&acc[3], (double)r);
  r = blk_reduce(ssb * ssb, sred); if (threadIdx.x == 0) atomicAdd(&acc[4], (double)r);
}

// -------- Gram matrix G = zc zc^T (32x32): accumulate ||G||_F^2 --------
// ||cov||_F^2 = ||G||_F^2 / 31^2  (trace identity) -- avoids 8192x8192 cov.
__global__ __launch_bounds__(256) void k_gram(
    const float* __restrict__ za, const float* __restrict__ zb,
    const float* __restrict__ ma, const float* __restrict__ mb,
    double* __restrict__ acc) {
  __shared__ float sred[256];
  int e = blockIdx.x;            // 0..1023
  int p = e >> 5, q = e & 31;
  const float* z = blockIdx.y ? zb : za;
  const float* m = blockIdx.y ? mb : ma;
  float s = 0.f;
  for (int i = threadIdx.x; i < DZ; i += 256)
    s += (z[p * DZ + i] - m[i]) * (z[q * DZ + i] - m[i]);
  float G = blk_reduce(s, sred);
  if (threadIdx.x == 0) atomicAdd(&acc[5 + blockIdx.y], (double)G * (double)G);
}

// -------- squared row norms of feature maps --------
__global__ __launch_bounds__(64) void k_norms(
    const float* __restrict__ zgf, const float* __restrict__ zlf,
    float* __restrict__ ng, float* __restrict__ nl) {
  int r = blockIdx.x;
  const float* src; float* dst;
  if (r < BATCH * LG) { src = zgf + (size_t)r * CH; dst = ng + r; }
  else { int rr = r - BATCH * LG; src = zlf + (size_t)rr * CH; dst = nl + rr; }
  float s = 0.f;
  for (int j = threadIdx.x; j < CH; j += 64) { float v = src[j]; s += v * v; }
  for (int off = 32; off > 0; off >>= 1) s += __shfl_down(s, off);
  if (threadIdx.x == 0) *dst = s;
}

// -------- feature-space cdist tiles + fused row/col NN argmin --------
// Tile 64 (global rows) x 128 (local cols), block 256 = 16x16, thread tile 4x8.
__global__ __launch_bounds__(256) void k_feat_nn(
    const float* __restrict__ zgf, const float* __restrict__ zlf,
    const float* __restrict__ ng, const float* __restrict__ nl,
    unsigned long long* __restrict__ rowNN, unsigned long long* __restrict__ colNN) {
  const int b = blockIdx.z;
  const int row0 = blockIdx.x * 64;
  const int col0 = blockIdx.y * 128;
  const int tid = threadIdx.x;
  const int tx = tid & 15, ty = tid >> 4;

  __shared__ float As[64][20];    // [row][k], pad to 20 floats
  __shared__ float Bs[128][20];
  __shared__ float Ds[64][130];   // d^2 tile, pad 130

  const float* Ag = zgf + ((size_t)b * LG + row0) * CH;
  const float* Bg = zlf + ((size_t)b * LL + col0) * CH;

  float acc[4][8];
  #pragma unroll
  for (int i = 0; i < 4; ++i)
    #pragma unroll
    for (int j = 0; j < 8; ++j) acc[i][j] = 0.f;

  const int ar = tid >> 2;        // 0..63
  const int ak = (tid & 3) * 4;   // 0,4,8,12

  for (int k0 = 0; k0 < CH; k0 += 16) {
    float4 av  = *(const float4*)(Ag + (size_t)ar * CH + k0 + ak);
    float4 bv0 = *(const float4*)(Bg + (size_t)ar * CH + k0 + ak);
    float4 bv1 = *(const float4*)(Bg + (size_t)(ar + 64) * CH + k0 + ak);
    __syncthreads();
    *(float4*)&As[ar][ak] = av;
    *(float4*)&Bs[ar][ak] = bv0;
    *(float4*)&Bs[ar + 64][ak] = bv1;
    __syncthreads();
    #pragma unroll
    for (int k = 0; k < 16; ++k) {
      float a0 = As[ty][k], a1 = As[ty + 16][k], a2 = As[ty + 32][k], a3 = As[ty + 48][k];
      float bv[8];
      #pragma unroll
      for (int j = 0; j < 8; ++j) bv[j] = Bs[tx + 16 * j][k];
      #pragma unroll
      for (int j = 0; j < 8; ++j) {
        acc[0][j] += a0 * bv[j];
        acc[1][j] += a1 * bv[j];
        acc[2][j] += a2 * bv[j];
        acc[3][j] += a3 * bv[j];
      }
    }
  }

  float ngr[4], nlc[8];
  #pragma unroll
  for (int i = 0; i < 4; ++i) ngr[i] = ng[b * LG + row0 + ty + 16 * i];
  #pragma unroll
  for (int j = 0; j < 8; ++j) nlc[j] = nl[b * LL + col0 + tx + 16 * j];
  #pragma unroll
  for (int i = 0; i < 4; ++i)
    #pragma unroll
    for (int j = 0; j < 8; ++j)
      Ds[ty + 16 * i][tx + 16 * j] = fmaxf(ngr[i] + nlc[j] - 2.f * acc[i][j], 0.f);
  __syncthreads();

  if (tid < 64) {
    unsigned long long best = ~0ull;
    for (int c = 0; c < 128; ++c) {
      unsigned long long p =
          ((unsigned long long)__float_as_uint(Ds[tid][c]) << 32) | (unsigned int)(col0 + c);
      best = p < best ? p : best;
    }
    atomicMin(&rowNN[(size_t)b * LG + row0 + tid], best);
  } else if (tid < 192) {
    int c = tid - 64;
    unsigned long long best = ~0ull;
    for (int r = 0; r < 64; ++r) {
      unsigned long long p =
          ((unsigned long long)__float_as_uint(Ds[r][c]) << 32) | (unsigned int)(row0 + r);
      best = p < best ? p : best;
    }
    atomicMin(&colNN[(size_t)b * LL + col0 + c], best);
  }
}

// -------- top-M selection (smallest NN dist, tie -> lowest location) + pair MSE --------
__global__ __launch_bounds__(256) void k_feat_sel(
    const float* __restrict__ zgf, const float* __restrict__ zlf,
    const unsigned long long* __restrict__ rowNN, const unsigned long long* __restrict__ colNN,
    double* __restrict__ acc) {
  int b = blockIdx.x, dir = blockIdx.y;
  int L1 = dir == 0 ? LG : LL;
  int M  = dir == 0 ? 20 : 4;
  const unsigned long long* src = dir == 0 ? rowNN + (size_t)b * LG : colNN + (size_t)b * LL;
  const float* fin  = dir == 0 ? zgf + (size_t)b * LG * CH : zlf + (size_t)b * LL * CH;
  const float* fcan = dir == 0 ? zlf + (size_t)b * LL * CH : zgf + (size_t)b * LG * CH;

  __shared__ unsigned long long selp[LG];
  __shared__ unsigned int nnm[LG];
  __shared__ unsigned long long red[256];
  __shared__ float fred[256];
  __shared__ unsigned int plist[40];

  int tid = threadIdx.x;
  for (int l = tid; l < L1; l += 256) {
    unsigned long long p = src[l];
    selp[l] = (p & 0xFFFFFFFF00000000ull) | (unsigned int)l;  // order by (d2, location)
    nnm[l] = (unsigned int)(p & 0xFFFFFFFFu);
  }
  __syncthreads();
  for (int r = 0; r < M; ++r) {
    unsigned long long v = ~0ull;
    for (int l = tid; l < L1; l += 256) { unsigned long long e = selp[l]; v = e < v ? e : v; }
    red[tid] = v; __syncthreads();
    for (int s = 128; s > 0; s >>= 1) {
      if (tid < s) { if (red[tid + s] < red[tid]) red[tid] = red[tid + s]; }
      __syncthreads();
    }
    if (tid == 0) {
      unsigned int ls = (unsigned int)(red[0] & 0xFFFFFFFFu);
      plist[2 * r] = ls; plist[2 * r + 1] = nnm[ls];
      selp[ls] = ~0ull;
    }
    __syncthreads();
  }
  float part = 0.f;
  for (int r = 0; r < M; ++r) {
    const float* a = fin  + (size_t)plist[2 * r] * CH;
    const float* c = fcan + (size_t)plist[2 * r + 1] * CH;
    for (int j = tid; j < CH; j += 256) { float d = a[j] - c[j]; part += d * d; }
  }
  fred[tid] = part; __syncthreads();
  for (int s = 128; s > 0; s >>= 1) { if (tid < s) fred[tid] += fred[tid + s]; __syncthreads(); }
  if (tid == 0) atomicAdd(&acc[7 + dir], (double)fred[0]);
}

// -------- grid-space NN (2-D coords) + selection + pair MSE (features gathered) --------
__global__ __launch_bounds__(256) void k_grid_nn(
    const float* __restrict__ zgf, const float* __restrict__ zlf,
    const float* __restrict__ gg, const float* __restrict__ gl,
    double* __restrict__ acc) {
  int b = blockIdx.x, dir = blockIdx.y;
  int L1 = dir == 0 ? LG : LL;
  int L2 = dir == 0 ? LL : LG;
  int M  = dir == 0 ? 20 : 4;
  const float* gin  = dir == 0 ? gg + (size_t)b * LG * 2 : gl + (size_t)b * LL * 2;
  const float* gcan = dir == 0 ? gl + (size_t)b * LL * 2 : gg + (size_t)b * LG * 2;
  const float* fin  = dir == 0 ? zgf + (size_t)b * LG * CH : zlf + (size_t)b * LL * CH;
  const float* fcan = dir == 0 ? zlf + (size_t)b * LL * CH : zgf + (size_t)b * LG * CH;

  __shared__ float cxy[2 * LG];
  __shared__ unsigned long long selp[LG];
  __shared__ unsigned int nnm[LG];
  __shared__ unsigned long long red[256];
  __shared__ float fred[256];
  __shared__ unsigned int plist[40];

  int tid = threadIdx.x;
  for (int i = tid; i < 2 * L2; i += 256) cxy[i] = gcan[i];
  __syncthreads();
  for (int l = tid; l < L1; l += 256) {
    float x = gin[2 * l], y = gin[2 * l + 1];
    float bd = __int_as_float(0x7f7fffff); unsigned int bi = 0;
    for (int m2 = 0; m2 < L2; ++m2) {
      float dx = x - cxy[2 * m2], dy = y - cxy[2 * m2 + 1];
      float d2 = dx * dx + dy * dy;
      if (d2 < bd) { bd = d2; bi = (unsigned int)m2; }   // strict < : first-min like argmin
    }
    selp[l] = ((unsigned long long)__float_as_uint(bd) << 32) | (unsigned int)l;
    nnm[l] = bi;
  }
  __syncthreads();
  for (int r = 0; r < M; ++r) {
    unsigned long long v = ~0ull;
    for (int l = tid; l < L1; l += 256) { unsigned long long e = selp[l]; v = e < v ? e : v; }
    red[tid] = v; __syncthreads();
    for (int s = 128; s > 0; s >>= 1) {
      if (tid < s) { if (red[tid + s] < red[tid]) red[tid] = red[tid + s]; }
      __syncthreads();
    }
    if (tid == 0) {
      unsigned int ls = (unsigned int)(red[0] & 0xFFFFFFFFu);
      plist[2 * r] = ls; plist[2 * r + 1] = nnm[ls];
      selp[ls] = ~0ull;
    }
    __syncthreads();
  }
  float part = 0.f;
  for (int r = 0; r < M; ++r) {
    const float* a = fin  + (size_t)plist[2 * r] * CH;
    const float* c = fcan + (size_t)plist[2 * r + 1] * CH;
    for (int j = tid; j < CH; j += 256) { float d = a[j] - c[j]; part += d * d; }
  }
  fred[tid] = part; __syncthreads();
  for (int s = 128; s > 0; s >>= 1) { if (tid < s) fred[tid] += fred[tid + s]; __syncthreads(); }
  if (tid == 0) atomicAdd(&acc[9 + dir], (double)fred[0]);
}

// -------- final combine --------
__global__ void k_final(const double* __restrict__ acc, float* __restrict__ out) {
  double inv_g = acc[0] / (32.0 * 8192.0);
  double v = 0.5 * (acc[1] + acc[2]) / 8192.0;
  double c = (acc[5] - acc[3] + acc[6] - acc[4]) / (961.0 * 8192.0);
  double gloss = 25.0 * inv_g + 25.0 * v + c;
  double mfg = acc[7] / (32.0 * 20.0 * 512.0);
  double mfl = acc[8] / (32.0 * 4.0 * 512.0);
  double mgg = acc[9] / (32.0 * 20.0 * 512.0);
  double mgl = acc[10] / (32.0 * 4.0 * 512.0);
  double lloss = 25.0 * (0.5 * (mfg + mfl) + 0.5 * (mgg + mgl));
  out[0] = (float)(0.25 * gloss + 0.75 * lloss);
}

extern "C" void kernel_launch(void* const* d_in, const int* in_sizes, int n_in,
                              void* d_out, int out_size, void* d_ws, size_t ws_size,
                              hipStream_t stream) {
  const float* zg  = (const float*)d_in[0];
  const float* zl  = (const float*)d_in[1];
  const float* zgf = (const float*)d_in[2];
  const float* zlf = (const float*)d_in[3];
  const float* gg  = (const float*)d_in[4];
  const float* glo = (const float*)d_in[5];

  char* ws = (char*)d_ws;
  double* acc = (double*)(ws + OFF_ACC);
  float* ma = (float*)(ws + OFF_MA);
  float* mb = (float*)(ws + OFF_MB);
  float* ng = (float*)(ws + OFF_NG);
  float* nl = (float*)(ws + OFF_NL);
  unsigned long long* rowNN = (unsigned long long*)(ws + OFF_ROWNN);
  unsigned long long* colNN = (unsigned long long*)(ws + OFF_COLNN);

  hipMemsetAsync(ws + OFF_ACC, 0, 16 * sizeof(double), stream);
  hipMemsetAsync(ws + OFF_ROWNN, 0xFF, (size_t)8 * BATCH * (LG + LL), stream);

  k_global_stats<<<DZ / 256, 256, 0, stream>>>(zg, zl, acc, ma, mb);
  k_gram<<<dim3(1024, 2), 256, 0, stream>>>(zg, zl, ma, mb, acc);
  k_norms<<<BATCH * (LG + LL), 64, 0, stream>>>(zgf, zlf, ng, nl);
  k_feat_nn<<<dim3(LG / 64, LL / 128, BATCH), 256, 0, stream>>>(zgf, zlf, ng, nl, rowNN, colNN);
  k_feat_sel<<<dim3(BATCH, 2), 256, 0, stream>>>(zgf, zlf, rowNN, colNN, acc);
  k_grid_nn<<<dim3(BATCH, 2), 256, 0, stream>>>(zgf, zlf, gg, glo, acc);
  k_final<<<1, 1, 0, stream>>>(acc, (float*)d_out);
}

// Round 2
// 214.874 us; speedup vs baseline: 1.5138x; 1.5138x over previous
//
#include <hip/hip_runtime.h>
#include <hip/hip_bf16.h>

#define BATCH 32
#define DZ    8192
#define LG    576
#define LL    256
#define CH    512

// ---- unified ws layout (byte offsets) ----
#define OFF_ACC    0                         // double[16]
#define OFF_MA     128                       // float[DZ]
#define OFF_MB     (OFF_MA + 4*DZ)           // float[DZ]
#define OFF_NG     (OFF_MB + 4*DZ)           // float[BATCH*LG]
#define OFF_NL     (OFF_NG + 4*BATCH*LG)     // float[BATCH*LL]
#define OFF_ROWNN  (OFF_NL + 4*BATCH*LL)     // u64[BATCH*LG]
#define OFF_COLNN  (OFF_ROWNN + 8*BATCH*LG)  // u64[BATCH*LL]
#define OFF_ABF    (OFF_COLNN + 8*BATCH*LL)  // bf16 bits [BATCH*LG*CH]
#define OFF_BBF    (OFF_ABF + 2*BATCH*LG*CH) // bf16 bits [BATCH*LL*CH]
#define WS_NEED    (OFF_BBF + 2*(size_t)BATCH*LL*CH)

// acc: 0 inv_global, 1 var_a, 2 var_b, 3 diag_a, 4 diag_b, 5 G2_a, 6 G2_b,
//      7 feat_g, 8 feat_l, 9 grid_g, 10 grid_l

typedef __attribute__((ext_vector_type(8))) short bf16x8;
typedef __attribute__((ext_vector_type(4))) float f32x4;

__device__ __forceinline__ unsigned short f2bf(float x) {
  union { __hip_bfloat16 h; unsigned short u; } cv;
  cv.h = __float2bfloat16(x);
  return cv.u;
}

// -------- global VICReg stats (wave-reduce, 128 blocks) --------
__global__ __launch_bounds__(64) void k_global_stats(
    const float* __restrict__ za, const float* __restrict__ zb,
    double* __restrict__ acc, float* __restrict__ ma, float* __restrict__ mb) {
  int i = blockIdx.x * 64 + threadIdx.x;
  float sa = 0.f, qa = 0.f, sb = 0.f, qb = 0.f, si = 0.f;
  #pragma unroll 8
  for (int b = 0; b < BATCH; ++b) {
    float va = za[(size_t)b * DZ + i];
    float vb = zb[(size_t)b * DZ + i];
    sa += va; qa += va * va;
    sb += vb; qb += vb * vb;
    float d = va - vb; si += d * d;
  }
  ma[i] = sa * (1.f / 32.f);
  mb[i] = sb * (1.f / 32.f);
  float ssa = qa - sa * sa * (1.f / 32.f);
  float ssb = qb - sb * sb * (1.f / 32.f);
  float ra = fmaxf(0.f, 1.f - sqrtf(ssa * (1.f / 31.f) + 1e-4f));
  float rb = fmaxf(0.f, 1.f - sqrtf(ssb * (1.f / 31.f) + 1e-4f));
  float v0 = si, v1 = ra, v2 = rb, v3 = ssa * ssa, v4 = ssb * ssb;
  for (int off = 32; off; off >>= 1) {
    v0 += __shfl_down(v0, off); v1 += __shfl_down(v1, off);
    v2 += __shfl_down(v2, off); v3 += __shfl_down(v3, off);
    v4 += __shfl_down(v4, off);
  }
  if (threadIdx.x == 0) {
    atomicAdd(&acc[0], (double)v0); atomicAdd(&acc[1], (double)v1);
    atomicAdd(&acc[2], (double)v2); atomicAdd(&acc[3], (double)v3);
    atomicAdd(&acc[4], (double)v4);
  }
}

// -------- Gram G = zc zc^T (32x32), ||G||_F^2  (||cov||_F^2 = ||G||_F^2/31^2) ----
__global__ __launch_bounds__(256) void k_gram(
    const float* __restrict__ za, const float* __restrict__ zb,
    const float* __restrict__ ma, const float* __restrict__ mb,
    double* __restrict__ acc) {
  int e = blockIdx.x;            // 0..1023
  int p = e >> 5, q = e & 31;
  const float* z = blockIdx.y ? zb : za;
  const float* m = blockIdx.y ? mb : ma;
  float s = 0.f;
  for (int i = threadIdx.x; i < DZ; i += 256)
    s += (z[p * DZ + i] - m[i]) * (z[q * DZ + i] - m[i]);
  for (int off = 32; off; off >>= 1) s += __shfl_down(s, off);
  __shared__ float w4[4];
  int lane = threadIdx.x & 63, wv = threadIdx.x >> 6;
  if (lane == 0) w4[wv] = s;
  __syncthreads();
  if (threadIdx.x == 0) {
    float G = w4[0] + w4[1] + w4[2] + w4[3];
    atomicAdd(&acc[5 + blockIdx.y], (double)G * (double)G);
  }
}

// -------- prep: fp32 -> bf16 copies + fp32 row norms (one HBM pass) --------
__global__ __launch_bounds__(256) void k_prep(
    const float* __restrict__ zgf, const float* __restrict__ zlf,
    unsigned short* __restrict__ Abf, unsigned short* __restrict__ Bbf,
    float* __restrict__ ng, float* __restrict__ nl) {
  int row = blockIdx.x * 4 + (threadIdx.x >> 6);
  int lane = threadIdx.x & 63;
  const float* src; unsigned short* dst; float* nrm;
  if (row < BATCH * LG) {
    src = zgf + (size_t)row * CH; dst = Abf + (size_t)row * CH; nrm = ng + row;
  } else {
    int rr = row - BATCH * LG;
    src = zlf + (size_t)rr * CH; dst = Bbf + (size_t)rr * CH; nrm = nl + rr;
  }
  const float4* s4 = (const float4*)src;
  float4 v0 = s4[lane * 2], v1 = s4[lane * 2 + 1];
  float ss = v0.x * v0.x + v0.y * v0.y + v0.z * v0.z + v0.w * v0.w +
             v1.x * v1.x + v1.y * v1.y + v1.z * v1.z + v1.w * v1.w;
  union { unsigned short h[8]; uint4 u; } pk;
  pk.h[0] = f2bf(v0.x); pk.h[1] = f2bf(v0.y); pk.h[2] = f2bf(v0.z); pk.h[3] = f2bf(v0.w);
  pk.h[4] = f2bf(v1.x); pk.h[5] = f2bf(v1.y); pk.h[6] = f2bf(v1.z); pk.h[7] = f2bf(v1.w);
  *(uint4*)(dst + lane * 8) = pk.u;
  for (int off = 32; off; off >>= 1) ss += __shfl_down(ss, off);
  if (lane == 0) *nrm = ss;
}

// -------- feature-space cdist via bf16 MFMA + fused NN argmin --------
// Block: 256 thr = 4 waves; block tile 64x64; wave tile 32x32 (2x2 of 16x16x32).
__global__ __launch_bounds__(256) void k_feat_mfma(
    const unsigned short* __restrict__ Abf, const unsigned short* __restrict__ Bbf,
    const float* __restrict__ ng, const float* __restrict__ nl,
    unsigned long long* __restrict__ rowNN, unsigned long long* __restrict__ colNN) {
  const int b = blockIdx.z;
  const int row0 = blockIdx.x * 64;
  const int col0 = blockIdx.y * 64;
  const int tid = threadIdx.x;
  const int wave = tid >> 6, lane = tid & 63;
  const int m16 = lane & 15, quad = lane >> 4;
  const int wm = wave >> 1, wn = wave & 1;

  __shared__ unsigned short As[64][72];   // stride 72: 16B-aligned b128, 2-way banks
  __shared__ unsigned short Bs[64][72];

  const unsigned short* Ag = Abf + ((size_t)(b * LG + row0)) * CH;
  const unsigned short* Bg = Bbf + ((size_t)(b * LL + col0)) * CH;

  const int sr = tid >> 2;      // staging row 0..63
  const int sq = tid & 3;       // 16-elem col chunk

  f32x4 acc[2][2] = {};

  for (int k0 = 0; k0 < CH; k0 += 64) {
    uint4 a0 = *(const uint4*)(Ag + (size_t)sr * CH + k0 + sq * 16);
    uint4 a1 = *(const uint4*)(Ag + (size_t)sr * CH + k0 + sq * 16 + 8);
    uint4 b0 = *(const uint4*)(Bg + (size_t)sr * CH + k0 + sq * 16);
    uint4 b1 = *(const uint4*)(Bg + (size_t)sr * CH + k0 + sq * 16 + 8);
    __syncthreads();
    *(uint4*)&As[sr][sq * 16] = a0; *(uint4*)&As[sr][sq * 16 + 8] = a1;
    *(uint4*)&Bs[sr][sq * 16] = b0; *(uint4*)&Bs[sr][sq * 16 + 8] = b1;
    __syncthreads();
    #pragma unroll
    for (int kk = 0; kk < 64; kk += 32) {
      bf16x8 af0 = *(const bf16x8*)&As[wm * 32 + m16][kk + quad * 8];
      bf16x8 af1 = *(const bf16x8*)&As[wm * 32 + 16 + m16][kk + quad * 8];
      bf16x8 bf0 = *(const bf16x8*)&Bs[wn * 32 + m16][kk + quad * 8];
      bf16x8 bf1 = *(const bf16x8*)&Bs[wn * 32 + 16 + m16][kk + quad * 8];
      acc[0][0] = __builtin_amdgcn_mfma_f32_16x16x32_bf16(af0, bf0, acc[0][0], 0, 0, 0);
      acc[0][1] = __builtin_amdgcn_mfma_f32_16x16x32_bf16(af0, bf1, acc[0][1], 0, 0, 0);
      acc[1][0] = __builtin_amdgcn_mfma_f32_16x16x32_bf16(af1, bf0, acc[1][0], 0, 0, 0);
      acc[1][1] = __builtin_amdgcn_mfma_f32_16x16x32_bf16(af1, bf1, acc[1][1], 0, 0, 0);
    }
  }

  // ---- epilogue: d^2 = |a|^2 + |b|^2 - 2ab ; packed (d2,idx) min-reduce ----
  float na[2][4], nb[2];
  #pragma unroll
  for (int i = 0; i < 2; ++i)
    #pragma unroll
    for (int r = 0; r < 4; ++r)
      na[i][r] = ng[b * LG + row0 + wm * 32 + i * 16 + quad * 4 + r];
  #pragma unroll
  for (int j = 0; j < 2; ++j)
    nb[j] = nl[b * LL + col0 + wn * 32 + j * 16 + m16];

  // row NN (min over cols): reduce within 16-lane groups (same quad = same row)
  #pragma unroll
  for (int i = 0; i < 2; ++i) {
    #pragma unroll
    for (int r = 0; r < 4; ++r) {
      float d0 = fmaxf(na[i][r] + nb[0] - 2.f * acc[i][0][r], 0.f);
      float d1 = fmaxf(na[i][r] + nb[1] - 2.f * acc[i][1][r], 0.f);
      unsigned c0 = (unsigned)(col0 + wn * 32 + m16);
      unsigned long long p0 = (((unsigned long long)__float_as_uint(d0)) << 32) | c0;
      unsigned long long p1 = (((unsigned long long)__float_as_uint(d1)) << 32) | (c0 + 16);
      unsigned long long p = p0 < p1 ? p0 : p1;
      #pragma unroll
      for (int s = 1; s < 16; s <<= 1) {
        unsigned long long q = __shfl_xor(p, s);
        p = q < p ? q : p;
      }
      if (m16 == 0)
        atomicMin(&rowNN[(size_t)b * LG + row0 + wm * 32 + i * 16 + quad * 4 + r], p);
    }
  }
  // col NN (min over rows): reduce across quads (same m16 = same col)
  #pragma unroll
  for (int j = 0; j < 2; ++j) {
    unsigned long long p = ~0ull;
    #pragma unroll
    for (int i = 0; i < 2; ++i) {
      #pragma unroll
      for (int r = 0; r < 4; ++r) {
        float d = fmaxf(na[i][r] + nb[j] - 2.f * acc[i][j][r], 0.f);
        unsigned rg = (unsigned)(row0 + wm * 32 + i * 16 + quad * 4 + r);
        unsigned long long pr = (((unsigned long long)__float_as_uint(d)) << 32) | rg;
        p = pr < p ? pr : p;
      }
    }
    unsigned long long q = __shfl_xor(p, 16); p = q < p ? q : p;
    q = __shfl_xor(p, 32); p = q < p ? q : p;
    if (quad == 0)
      atomicMin(&colNN[(size_t)b * LL + col0 + wn * 32 + j * 16 + m16], p);
  }
}

// -------- FALLBACK (small ws): fp32 VALU cdist + NN (round-1 kernel) --------
__global__ __launch_bounds__(64) void k_norms(
    const float* __restrict__ zgf, const float* __restrict__ zlf,
    float* __restrict__ ng, float* __restrict__ nl) {
  int r = blockIdx.x;
  const float* src; float* dst;
  if (r < BATCH * LG) { src = zgf + (size_t)r * CH; dst = ng + r; }
  else { int rr = r - BATCH * LG; src = zlf + (size_t)rr * CH; dst = nl + rr; }
  float s = 0.f;
  for (int j = threadIdx.x; j < CH; j += 64) { float v = src[j]; s += v * v; }
  for (int off = 32; off > 0; off >>= 1) s += __shfl_down(s, off);
  if (threadIdx.x == 0) *dst = s;
}

__global__ __launch_bounds__(256) void k_feat_nn(
    const float* __restrict__ zgf, const float* __restrict__ zlf,
    const float* __restrict__ ng, const float* __restrict__ nl,
    unsigned long long* __restrict__ rowNN, unsigned long long* __restrict__ colNN) {
  const int b = blockIdx.z;
  const int row0 = blockIdx.x * 64;
  const int col0 = blockIdx.y * 128;
  const int tid = threadIdx.x;
  const int tx = tid & 15, ty = tid >> 4;
  __shared__ float As[64][20];
  __shared__ float Bs[128][20];
  __shared__ float Ds[64][130];
  const float* Ag = zgf + ((size_t)b * LG + row0) * CH;
  const float* Bg = zlf + ((size_t)b * LL + col0) * CH;
  float acc[4][8];
  #pragma unroll
  for (int i = 0; i < 4; ++i)
    #pragma unroll
    for (int j = 0; j < 8; ++j) acc[i][j] = 0.f;
  const int ar = tid >> 2;
  const int ak = (tid & 3) * 4;
  for (int k0 = 0; k0 < CH; k0 += 16) {
    float4 av  = *(const float4*)(Ag + (size_t)ar * CH + k0 + ak);
    float4 bv0 = *(const float4*)(Bg + (size_t)ar * CH + k0 + ak);
    float4 bv1 = *(const float4*)(Bg + (size_t)(ar + 64) * CH + k0 + ak);
    __syncthreads();
    *(float4*)&As[ar][ak] = av;
    *(float4*)&Bs[ar][ak] = bv0;
    *(float4*)&Bs[ar + 64][ak] = bv1;
    __syncthreads();
    #pragma unroll
    for (int k = 0; k < 16; ++k) {
      float a0 = As[ty][k], a1 = As[ty + 16][k], a2 = As[ty + 32][k], a3 = As[ty + 48][k];
      float bv[8];
      #pragma unroll
      for (int j = 0; j < 8; ++j) bv[j] = Bs[tx + 16 * j][k];
      #pragma unroll
      for (int j = 0; j < 8; ++j) {
        acc[0][j] += a0 * bv[j]; acc[1][j] += a1 * bv[j];
        acc[2][j] += a2 * bv[j]; acc[3][j] += a3 * bv[j];
      }
    }
  }
  float ngr[4], nlc[8];
  #pragma unroll
  for (int i = 0; i < 4; ++i) ngr[i] = ng[b * LG + row0 + ty + 16 * i];
  #pragma unroll
  for (int j = 0; j < 8; ++j) nlc[j] = nl[b * LL + col0 + tx + 16 * j];
  #pragma unroll
  for (int i = 0; i < 4; ++i)
    #pragma unroll
    for (int j = 0; j < 8; ++j)
      Ds[ty + 16 * i][tx + 16 * j] = fmaxf(ngr[i] + nlc[j] - 2.f * acc[i][j], 0.f);
  __syncthreads();
  if (tid < 64) {
    unsigned long long best = ~0ull;
    for (int c = 0; c < 128; ++c) {
      unsigned long long p =
          ((unsigned long long)__float_as_uint(Ds[tid][c]) << 32) | (unsigned)(col0 + c);
      best = p < best ? p : best;
    }
    atomicMin(&rowNN[(size_t)b * LG + row0 + tid], best);
  } else if (tid < 192) {
    int c = tid - 64;
    unsigned long long best = ~0ull;
    for (int r = 0; r < 64; ++r) {
      unsigned long long p =
          ((unsigned long long)__float_as_uint(Ds[r][c]) << 32) | (unsigned)(row0 + r);
      best = p < best ? p : best;
    }
    atomicMin(&colNN[(size_t)b * LL + col0 + c], best);
  }
}

// -------- merged selection + pair MSE (feat dirs use NN arrays; grid dirs compute) --
__global__ __launch_bounds__(256) void k_sel(
    const float* __restrict__ zgf, const float* __restrict__ zlf,
    const float* __restrict__ gg, const float* __restrict__ gl,
    const unsigned long long* __restrict__ rowNN, const unsigned long long* __restrict__ colNN,
    double* __restrict__ acc) {
  int b = blockIdx.x, v = blockIdx.y;   // v: 0 feat g, 1 feat l, 2 grid g, 3 grid l
  bool gdir = (v == 0 || v == 2);
  int L1 = gdir ? LG : LL;
  int L2 = gdir ? LL : LG;
  int M  = gdir ? 20 : 4;
  const float* fin  = gdir ? zgf + (size_t)b * LG * CH : zlf + (size_t)b * LL * CH;
  const float* fcan = gdir ? zlf + (size_t)b * LL * CH : zgf + (size_t)b * LG * CH;

  __shared__ unsigned long long selp[LG];
  __shared__ unsigned int nnm[LG];
  __shared__ float cxy[2 * LG];
  __shared__ unsigned long long wred[4];
  __shared__ float fred[4];
  __shared__ unsigned int plist[40];

  int tid = threadIdx.x, lane = tid & 63, wv = tid >> 6;

  if (v < 2) {
    const unsigned long long* src = (v == 0) ? rowNN + (size_t)b * LG : colNN + (size_t)b * LL;
    for (int l = tid; l < L1; l += 256) {
      unsigned long long p = src[l];
      selp[l] = (p & 0xFFFFFFFF00000000ull) | (unsigned)l;
      nnm[l] = (unsigned)(p & 0xFFFFFFFFu);
    }
  } else {
    const float* gin  = (v == 2) ? gg + (size_t)b * LG * 2 : gl + (size_t)b * LL * 2;
    const float* gcan = (v == 2) ? gl + (size_t)b * LL * 2 : gg + (size_t)b * LG * 2;
    for (int i = tid; i < 2 * L2; i += 256) cxy[i] = gcan[i];
    __syncthreads();
    for (int l = tid; l < L1; l += 256) {
      float x = gin[2 * l], y = gin[2 * l + 1];
      float bd = 3.4e38f; unsigned bi = 0;
      for (int m2 = 0; m2 < L2; ++m2) {
        float dx = x - cxy[2 * m2], dy = y - cxy[2 * m2 + 1];
        float d2 = dx * dx + dy * dy;
        if (d2 < bd) { bd = d2; bi = (unsigned)m2; }
      }
      selp[l] = ((unsigned long long)__float_as_uint(bd) << 32) | (unsigned)l;
      nnm[l] = bi;
    }
  }
  __syncthreads();
  for (int r = 0; r < M; ++r) {
    unsigned long long p = ~0ull;
    for (int l = tid; l < L1; l += 256) { unsigned long long e = selp[l]; p = e < p ? e : p; }
    for (int s = 32; s; s >>= 1) { unsigned long long q = __shfl_down(p, s); p = q < p ? q : p; }
    if (lane == 0) wred[wv] = p;
    __syncthreads();
    if (tid == 0) {
      unsigned long long m = wred[0];
      for (int w = 1; w < 4; ++w) m = wred[w] < m ? wred[w] : m;
      unsigned ls = (unsigned)(m & 0xFFFFFFFFu);
      plist[2 * r] = ls; plist[2 * r + 1] = nnm[ls];
      selp[ls] = ~0ull;
    }
    __syncthreads();
  }
  float part = 0.f;
  for (int r = 0; r < M; ++r) {
    const float* a = fin  + (size_t)plist[2 * r] * CH;
    const float* c = fcan + (size_t)plist[2 * r + 1] * CH;
    for (int j = tid; j < CH; j += 256) { float d = a[j] - c[j]; part += d * d; }
  }
  for (int s = 32; s; s >>= 1) part += __shfl_down(part, s);
  if (lane == 0) fred[wv] = part;
  __syncthreads();
  if (tid == 0)
    atomicAdd(&acc[7 + v], (double)(fred[0] + fred[1] + fred[2] + fred[3]));
}

// -------- final combine --------
__global__ void k_final(const double* __restrict__ acc, float* __restrict__ out) {
  double inv_g = acc[0] / (32.0 * 8192.0);
  double v = 0.5 * (acc[1] + acc[2]) / 8192.0;
  double c = (acc[5] - acc[3] + acc[6] - acc[4]) / (961.0 * 8192.0);
  double gloss = 25.0 * inv_g + 25.0 * v + c;
  double mfg = acc[7] / (32.0 * 20.0 * 512.0);
  double mfl = acc[8] / (32.0 * 4.0 * 512.0);
  double mgg = acc[9] / (32.0 * 20.0 * 512.0);
  double mgl = acc[10] / (32.0 * 4.0 * 512.0);
  double lloss = 25.0 * (0.5 * (mfg + mfl) + 0.5 * (mgg + mgl));
  out[0] = (float)(0.25 * gloss + 0.75 * lloss);
}

extern "C" void kernel_launch(void* const* d_in, const int* in_sizes, int n_in,
                              void* d_out, int out_size, void* d_ws, size_t ws_size,
                              hipStream_t stream) {
  const float* zg  = (const float*)d_in[0];
  const float* zl  = (const float*)d_in[1];
  const float* zgf = (const float*)d_in[2];
  const float* zlf = (const float*)d_in[3];
  const float* gg  = (const float*)d_in[4];
  const float* glo = (const float*)d_in[5];

  char* ws = (char*)d_ws;
  double* acc = (double*)(ws + OFF_ACC);
  float* ma = (float*)(ws + OFF_MA);
  float* mb = (float*)(ws + OFF_MB);
  float* ng = (float*)(ws + OFF_NG);
  float* nl = (float*)(ws + OFF_NL);
  unsigned long long* rowNN = (unsigned long long*)(ws + OFF_ROWNN);
  unsigned long long* colNN = (unsigned long long*)(ws + OFF_COLNN);
  unsigned short* Abf = (unsigned short*)(ws + OFF_ABF);
  unsigned short* Bbf = (unsigned short*)(ws + OFF_BBF);

  hipMemsetAsync(ws + OFF_ACC, 0, 16 * sizeof(double), stream);
  hipMemsetAsync(ws + OFF_ROWNN, 0xFF, (size_t)8 * BATCH * (LG + LL), stream);

  k_global_stats<<<DZ / 64, 64, 0, stream>>>(zg, zl, acc, ma, mb);
  k_gram<<<dim3(1024, 2), 256, 0, stream>>>(zg, zl, ma, mb, acc);

  if (ws_size >= WS_NEED) {
    k_prep<<<(BATCH * (LG + LL)) / 4, 256, 0, stream>>>(zgf, zlf, Abf, Bbf, ng, nl);
    k_feat_mfma<<<dim3(LG / 64, LL / 64, BATCH), 256, 0, stream>>>(Abf, Bbf, ng, nl, rowNN, colNN);
  } else {
    k_norms<<<BATCH * (LG + LL), 64, 0, stream>>>(zgf, zlf, ng, nl);
    k_feat_nn<<<dim3(LG / 64, LL / 128, BATCH), 256, 0, stream>>>(zgf, zlf, ng, nl, rowNN, colNN);
  }
  k_sel<<<dim3(BATCH, 4), 256, 0, stream>>>(zgf, zlf, gg, glo, rowNN, colNN, acc);
  k_final<<<1, 1, 0, stream>>>(acc, (float*)d_out);
}

// Round 3
// 193.553 us; speedup vs baseline: 1.6805x; 1.1102x over previous
//
#include <hip/hip_runtime.h>
#include <hip/hip_bf16.h>

#define BATCH 32
#define DZ    8192
#define LG    576
#define LL    256
#define CH    512

// ---- ws layout (byte offsets) ----
#define OFF_ACC    0                          // double[16] = 128 B
#define OFF_S      128                        // float[2*1024] raw Gram S (a,b)
#define OFF_NG     (OFF_S + 4*2048)           // float[BATCH*LG]
#define OFF_NL     (OFF_NG + 4*BATCH*LG)      // float[BATCH*LL]
#define OFF_ROWNN  (OFF_NL + 4*BATCH*LL)      // u64[BATCH*LG]
#define OFF_COLNN  (OFF_ROWNN + 8*BATCH*LG)   // u64[BATCH*LL]
#define OFF_ABF    (OFF_COLNN + 8*BATCH*LL)   // bf16 bits [BATCH*LG*CH]
#define OFF_BBF    (OFF_ABF + 2*BATCH*LG*CH)  // bf16 bits [BATCH*LL*CH]
#define WS_NEED    (OFF_BBF + 2*(size_t)BATCH*LL*CH)

// acc: 0 inv_global, 1 var_a, 2 var_b, 3 diag_a, 4 diag_b, (5,6 unused),
//      7 feat_g, 8 feat_l, 9 grid_g, 10 grid_l

typedef __attribute__((ext_vector_type(8))) short bf16x8;
typedef __attribute__((ext_vector_type(4))) float f32x4;

__device__ __forceinline__ unsigned short f2bf(float x) {
  union { __hip_bfloat16 h; unsigned short u; } cv;
  cv.h = __float2bfloat16(x);
  return cv.u;
}

// -------- global VICReg stats: inv mse, var hinge, diag(cov)^2 --------
__global__ __launch_bounds__(64) void k_global_stats(
    const float* __restrict__ za, const float* __restrict__ zb,
    double* __restrict__ acc) {
  int i = blockIdx.x * 64 + threadIdx.x;
  float sa = 0.f, qa = 0.f, sb = 0.f, qb = 0.f, si = 0.f;
  #pragma unroll 8
  for (int b = 0; b < BATCH; ++b) {
    float va = za[(size_t)b * DZ + i];
    float vb = zb[(size_t)b * DZ + i];
    sa += va; qa += va * va;
    sb += vb; qb += vb * vb;
    float d = va - vb; si += d * d;
  }
  float ssa = qa - sa * sa * (1.f / 32.f);   // centered SS = 31*var
  float ssb = qb - sb * sb * (1.f / 32.f);
  float ra = fmaxf(0.f, 1.f - sqrtf(ssa * (1.f / 31.f) + 1e-4f));
  float rb = fmaxf(0.f, 1.f - sqrtf(ssb * (1.f / 31.f) + 1e-4f));
  float v0 = si, v1 = ra, v2 = rb, v3 = ssa * ssa, v4 = ssb * ssb;
  for (int off = 32; off; off >>= 1) {
    v0 += __shfl_down(v0, off); v1 += __shfl_down(v1, off);
    v2 += __shfl_down(v2, off); v3 += __shfl_down(v3, off);
    v4 += __shfl_down(v4, off);
  }
  if (threadIdx.x == 0) {
    atomicAdd(&acc[0], (double)v0); atomicAdd(&acc[1], (double)v1);
    atomicAdd(&acc[2], (double)v2); atomicAdd(&acc[3], (double)v3);
    atomicAdd(&acc[4], (double)v4);
  }
}

// -------- raw sample Gram S = z z^T (32x32, symmetric): no mean dependency ----
// ||cov||_F^2 = ||G||_F^2/961 with G_pq = S_pq - t_p - t_q + u derived in k_final.
__global__ __launch_bounds__(256) void k_gram(
    const float* __restrict__ za, const float* __restrict__ zb,
    float* __restrict__ S) {
  int e = blockIdx.x;                  // 0..527: upper-triangular pair
  const float* z = blockIdx.y ? zb : za;
  float* Sz = S + blockIdx.y * 1024;
  int p = 0, rem = e;
  while (rem >= 32 - p) { rem -= 32 - p; ++p; }
  int q = p + rem;
  const float4* zp = (const float4*)(z + (size_t)p * DZ);
  const float4* zq = (const float4*)(z + (size_t)q * DZ);
  float s = 0.f;
  for (int i = threadIdx.x; i < DZ / 4; i += 256) {
    float4 a = zp[i], b = zq[i];
    s += a.x * b.x + a.y * b.y + a.z * b.z + a.w * b.w;
  }
  for (int off = 32; off; off >>= 1) s += __shfl_down(s, off);
  __shared__ float w4[4];
  int lane = threadIdx.x & 63, wv = threadIdx.x >> 6;
  if (lane == 0) w4[wv] = s;
  __syncthreads();
  if (threadIdx.x == 0) {
    float r = w4[0] + w4[1] + w4[2] + w4[3];
    Sz[p * 32 + q] = r;
    if (p != q) Sz[q * 32 + p] = r;
  }
}

// -------- prep: fp32 -> bf16 copies + fp32 row norms (one HBM pass) --------
__global__ __launch_bounds__(256) void k_prep(
    const float* __restrict__ zgf, const float* __restrict__ zlf,
    unsigned short* __restrict__ Abf, unsigned short* __restrict__ Bbf,
    float* __restrict__ ng, float* __restrict__ nl) {
  int row = blockIdx.x * 4 + (threadIdx.x >> 6);
  int lane = threadIdx.x & 63;
  const float* src; unsigned short* dst; float* nrm;
  if (row < BATCH * LG) {
    src = zgf + (size_t)row * CH; dst = Abf + (size_t)row * CH; nrm = ng + row;
  } else {
    int rr = row - BATCH * LG;
    src = zlf + (size_t)rr * CH; dst = Bbf + (size_t)rr * CH; nrm = nl + rr;
  }
  const float4* s4 = (const float4*)src;
  float4 v0 = s4[lane * 2], v1 = s4[lane * 2 + 1];
  float ss = v0.x * v0.x + v0.y * v0.y + v0.z * v0.z + v0.w * v0.w +
             v1.x * v1.x + v1.y * v1.y + v1.z * v1.z + v1.w * v1.w;
  union { unsigned short h[8]; uint4 u; } pk;
  pk.h[0] = f2bf(v0.x); pk.h[1] = f2bf(v0.y); pk.h[2] = f2bf(v0.z); pk.h[3] = f2bf(v0.w);
  pk.h[4] = f2bf(v1.x); pk.h[5] = f2bf(v1.y); pk.h[6] = f2bf(v1.z); pk.h[7] = f2bf(v1.w);
  *(uint4*)(dst + lane * 8) = pk.u;
  for (int off = 32; off; off >>= 1) ss += __shfl_down(ss, off);
  if (lane == 0) *nrm = ss;
}

// -------- feature-space cdist via bf16 MFMA + fused NN argmin --------
__global__ __launch_bounds__(256) void k_feat_mfma(
    const unsigned short* __restrict__ Abf, const unsigned short* __restrict__ Bbf,
    const float* __restrict__ ng, const float* __restrict__ nl,
    unsigned long long* __restrict__ rowNN, unsigned long long* __restrict__ colNN) {
  const int b = blockIdx.z;
  const int row0 = blockIdx.x * 64;
  const int col0 = blockIdx.y * 64;
  const int tid = threadIdx.x;
  const int wave = tid >> 6, lane = tid & 63;
  const int m16 = lane & 15, quad = lane >> 4;
  const int wm = wave >> 1, wn = wave & 1;

  __shared__ unsigned short As[64][72];
  __shared__ unsigned short Bs[64][72];

  const unsigned short* Ag = Abf + ((size_t)(b * LG + row0)) * CH;
  const unsigned short* Bg = Bbf + ((size_t)(b * LL + col0)) * CH;

  const int sr = tid >> 2;
  const int sq = tid & 3;

  f32x4 acc[2][2] = {};

  for (int k0 = 0; k0 < CH; k0 += 64) {
    uint4 a0 = *(const uint4*)(Ag + (size_t)sr * CH + k0 + sq * 16);
    uint4 a1 = *(const uint4*)(Ag + (size_t)sr * CH + k0 + sq * 16 + 8);
    uint4 b0 = *(const uint4*)(Bg + (size_t)sr * CH + k0 + sq * 16);
    uint4 b1 = *(const uint4*)(Bg + (size_t)sr * CH + k0 + sq * 16 + 8);
    __syncthreads();
    *(uint4*)&As[sr][sq * 16] = a0; *(uint4*)&As[sr][sq * 16 + 8] = a1;
    *(uint4*)&Bs[sr][sq * 16] = b0; *(uint4*)&Bs[sr][sq * 16 + 8] = b1;
    __syncthreads();
    #pragma unroll
    for (int kk = 0; kk < 64; kk += 32) {
      bf16x8 af0 = *(const bf16x8*)&As[wm * 32 + m16][kk + quad * 8];
      bf16x8 af1 = *(const bf16x8*)&As[wm * 32 + 16 + m16][kk + quad * 8];
      bf16x8 bf0 = *(const bf16x8*)&Bs[wn * 32 + m16][kk + quad * 8];
      bf16x8 bf1 = *(const bf16x8*)&Bs[wn * 32 + 16 + m16][kk + quad * 8];
      acc[0][0] = __builtin_amdgcn_mfma_f32_16x16x32_bf16(af0, bf0, acc[0][0], 0, 0, 0);
      acc[0][1] = __builtin_amdgcn_mfma_f32_16x16x32_bf16(af0, bf1, acc[0][1], 0, 0, 0);
      acc[1][0] = __builtin_amdgcn_mfma_f32_16x16x32_bf16(af1, bf0, acc[1][0], 0, 0, 0);
      acc[1][1] = __builtin_amdgcn_mfma_f32_16x16x32_bf16(af1, bf1, acc[1][1], 0, 0, 0);
    }
  }

  float na[2][4], nb[2];
  #pragma unroll
  for (int i = 0; i < 2; ++i)
    #pragma unroll
    for (int r = 0; r < 4; ++r)
      na[i][r] = ng[b * LG + row0 + wm * 32 + i * 16 + quad * 4 + r];
  #pragma unroll
  for (int j = 0; j < 2; ++j)
    nb[j] = nl[b * LL + col0 + wn * 32 + j * 16 + m16];

  #pragma unroll
  for (int i = 0; i < 2; ++i) {
    #pragma unroll
    for (int r = 0; r < 4; ++r) {
      float d0 = fmaxf(na[i][r] + nb[0] - 2.f * acc[i][0][r], 0.f);
      float d1 = fmaxf(na[i][r] + nb[1] - 2.f * acc[i][1][r], 0.f);
      unsigned c0 = (unsigned)(col0 + wn * 32 + m16);
      unsigned long long p0 = (((unsigned long long)__float_as_uint(d0)) << 32) | c0;
      unsigned long long p1 = (((unsigned long long)__float_as_uint(d1)) << 32) | (c0 + 16);
      unsigned long long p = p0 < p1 ? p0 : p1;
      #pragma unroll
      for (int s = 1; s < 16; s <<= 1) {
        unsigned long long q = __shfl_xor(p, s);
        p = q < p ? q : p;
      }
      if (m16 == 0)
        atomicMin(&rowNN[(size_t)b * LG + row0 + wm * 32 + i * 16 + quad * 4 + r], p);
    }
  }
  #pragma unroll
  for (int j = 0; j < 2; ++j) {
    unsigned long long p = ~0ull;
    #pragma unroll
    for (int i = 0; i < 2; ++i) {
      #pragma unroll
      for (int r = 0; r < 4; ++r) {
        float d = fmaxf(na[i][r] + nb[j] - 2.f * acc[i][j][r], 0.f);
        unsigned rg = (unsigned)(row0 + wm * 32 + i * 16 + quad * 4 + r);
        unsigned long long pr = (((unsigned long long)__float_as_uint(d)) << 32) | rg;
        p = pr < p ? pr : p;
      }
    }
    unsigned long long q = __shfl_xor(p, 16); p = q < p ? q : p;
    q = __shfl_xor(p, 32); p = q < p ? q : p;
    if (quad == 0)
      atomicMin(&colNN[(size_t)b * LL + col0 + wn * 32 + j * 16 + m16], p);
  }
}

// -------- FALLBACK (small ws): fp32 VALU cdist + NN --------
__global__ __launch_bounds__(64) void k_norms(
    const float* __restrict__ zgf, const float* __restrict__ zlf,
    float* __restrict__ ng, float* __restrict__ nl) {
  int r = blockIdx.x;
  const float* src; float* dst;
  if (r < BATCH * LG) { src = zgf + (size_t)r * CH; dst = ng + r; }
  else { int rr = r - BATCH * LG; src = zlf + (size_t)rr * CH; dst = nl + rr; }
  float s = 0.f;
  for (int j = threadIdx.x; j < CH; j += 64) { float v = src[j]; s += v * v; }
  for (int off = 32; off > 0; off >>= 1) s += __shfl_down(s, off);
  if (threadIdx.x == 0) *dst = s;
}

__global__ __launch_bounds__(256) void k_feat_nn(
    const float* __restrict__ zgf, const float* __restrict__ zlf,
    const float* __restrict__ ng, const float* __restrict__ nl,
    unsigned long long* __restrict__ rowNN, unsigned long long* __restrict__ colNN) {
  const int b = blockIdx.z;
  const int row0 = blockIdx.x * 64;
  const int col0 = blockIdx.y * 128;
  const int tid = threadIdx.x;
  const int tx = tid & 15, ty = tid >> 4;
  __shared__ float As[64][20];
  __shared__ float Bs[128][20];
  __shared__ float Ds[64][130];
  const float* Ag = zgf + ((size_t)b * LG + row0) * CH;
  const float* Bg = zlf + ((size_t)b * LL + col0) * CH;
  float acc[4][8];
  #pragma unroll
  for (int i = 0; i < 4; ++i)
    #pragma unroll
    for (int j = 0; j < 8; ++j) acc[i][j] = 0.f;
  const int ar = tid >> 2;
  const int ak = (tid & 3) * 4;
  for (int k0 = 0; k0 < CH; k0 += 16) {
    float4 av  = *(const float4*)(Ag + (size_t)ar * CH + k0 + ak);
    float4 bv0 = *(const float4*)(Bg + (size_t)ar * CH + k0 + ak);
    float4 bv1 = *(const float4*)(Bg + (size_t)(ar + 64) * CH + k0 + ak);
    __syncthreads();
    *(float4*)&As[ar][ak] = av;
    *(float4*)&Bs[ar][ak] = bv0;
    *(float4*)&Bs[ar + 64][ak] = bv1;
    __syncthreads();
    #pragma unroll
    for (int k = 0; k < 16; ++k) {
      float a0 = As[ty][k], a1 = As[ty + 16][k], a2 = As[ty + 32][k], a3 = As[ty + 48][k];
      float bv[8];
      #pragma unroll
      for (int j = 0; j < 8; ++j) bv[j] = Bs[tx + 16 * j][k];
      #pragma unroll
      for (int j = 0; j < 8; ++j) {
        acc[0][j] += a0 * bv[j]; acc[1][j] += a1 * bv[j];
        acc[2][j] += a2 * bv[j]; acc[3][j] += a3 * bv[j];
      }
    }
  }
  float ngr[4], nlc[8];
  #pragma unroll
  for (int i = 0; i < 4; ++i) ngr[i] = ng[b * LG + row0 + ty + 16 * i];
  #pragma unroll
  for (int j = 0; j < 8; ++j) nlc[j] = nl[b * LL + col0 + tx + 16 * j];
  #pragma unroll
  for (int i = 0; i < 4; ++i)
    #pragma unroll
    for (int j = 0; j < 8; ++j)
      Ds[ty + 16 * i][tx + 16 * j] = fmaxf(ngr[i] + nlc[j] - 2.f * acc[i][j], 0.f);
  __syncthreads();
  if (tid < 64) {
    unsigned long long best = ~0ull;
    for (int c = 0; c < 128; ++c) {
      unsigned long long p =
          ((unsigned long long)__float_as_uint(Ds[tid][c]) << 32) | (unsigned)(col0 + c);
      best = p < best ? p : best;
    }
    atomicMin(&rowNN[(size_t)b * LG + row0 + tid], best);
  } else if (tid < 192) {
    int c = tid - 64;
    unsigned long long best = ~0ull;
    for (int r = 0; r < 64; ++r) {
      unsigned long long p =
          ((unsigned long long)__float_as_uint(Ds[r][c]) << 32) | (unsigned)(row0 + r);
      best = p < best ? p : best;
    }
    atomicMin(&colNN[(size_t)b * LL + col0 + c], best);
  }
}

// -------- selection via rank counting + pair MSE (no serial top-M loop) --------
__global__ __launch_bounds__(256) void k_sel(
    const float* __restrict__ zgf, const float* __restrict__ zlf,
    const float* __restrict__ gg, const float* __restrict__ gl,
    const unsigned long long* __restrict__ rowNN, const unsigned long long* __restrict__ colNN,
    double* __restrict__ acc) {
  int b = blockIdx.x, v = blockIdx.y;   // 0 feat g, 1 feat l, 2 grid g, 3 grid l
  bool gdir = (v == 0 || v == 2);
  int L1 = gdir ? LG : LL;
  int L2 = gdir ? LL : LG;
  int M  = gdir ? 20 : 4;
  const float* fin  = gdir ? zgf + (size_t)b * LG * CH : zlf + (size_t)b * LL * CH;
  const float* fcan = gdir ? zlf + (size_t)b * LL * CH : zgf + (size_t)b * LG * CH;

  __shared__ unsigned long long keys[LG];
  __shared__ unsigned int nnm[LG];
  __shared__ float cxy[2 * LG];
  __shared__ unsigned int plist[40];
  __shared__ unsigned int cnt;
  __shared__ float fred[4];

  int tid = threadIdx.x, lane = tid & 63, wv = tid >> 6;
  if (tid == 0) cnt = 0;

  if (v < 2) {
    const unsigned long long* src = (v == 0) ? rowNN + (size_t)b * LG : colNN + (size_t)b * LL;
    for (int l = tid; l < L1; l += 256) {
      unsigned long long p = src[l];
      keys[l] = (p & 0xFFFFFFFF00000000ull) | (unsigned)l;
      nnm[l] = (unsigned)(p & 0xFFFFFFFFu);
    }
  } else {
    const float* gin  = (v == 2) ? gg + (size_t)b * LG * 2 : gl + (size_t)b * LL * 2;
    const float* gcan = (v == 2) ? gl + (size_t)b * LL * 2 : gg + (size_t)b * LG * 2;
    for (int i = tid; i < 2 * L2; i += 256) cxy[i] = gcan[i];
    __syncthreads();
    for (int l = tid; l < L1; l += 256) {
      float x = gin[2 * l], y = gin[2 * l + 1];
      float bd = 3.4e38f; unsigned bi = 0;
      const float2* c2 = (const float2*)cxy;
      #pragma unroll 4
      for (int m2 = 0; m2 < L2; ++m2) {
        float2 c = c2[m2];
        float dx = x - c.x, dy = y - c.y;
        float d2 = dx * dx + dy * dy;
        if (d2 < bd) { bd = d2; bi = (unsigned)m2; }
      }
      keys[l] = ((unsigned long long)__float_as_uint(bd) << 32) | (unsigned)l;
      nnm[l] = bi;
    }
  }
  __syncthreads();

  // rank counting: select iff #{keys smaller} < M (keys distinct -> exactly M)
  unsigned long long myk[3] = {~0ull, ~0ull, ~0ull};
  int myl[3] = {-1, -1, -1};
  #pragma unroll
  for (int s = 0; s < 3; ++s) {
    int l = tid + s * 256;
    if (l < L1) { myk[s] = keys[l]; myl[s] = l; }
  }
  int rk0 = 0, rk1 = 0, rk2 = 0;
  for (int j = 0; j < L1; ++j) {
    unsigned long long kj = keys[j];   // broadcast LDS read
    rk0 += (kj < myk[0]); rk1 += (kj < myk[1]); rk2 += (kj < myk[2]);
  }
  int rks[3] = {rk0, rk1, rk2};
  #pragma unroll
  for (int s = 0; s < 3; ++s) {
    if (myl[s] >= 0 && rks[s] < M) {
      unsigned slot = atomicAdd(&cnt, 1u);
      plist[2 * slot] = (unsigned)myl[s];
      plist[2 * slot + 1] = nnm[myl[s]];
    }
  }
  __syncthreads();

  float part = 0.f;
  for (int r = 0; r < M; ++r) {
    const float* a = fin  + (size_t)plist[2 * r] * CH;
    const float* c = fcan + (size_t)plist[2 * r + 1] * CH;
    for (int j = tid; j < CH; j += 256) { float d = a[j] - c[j]; part += d * d; }
  }
  for (int s = 32; s; s >>= 1) part += __shfl_down(part, s);
  if (lane == 0) fred[wv] = part;
  __syncthreads();
  if (tid == 0)
    atomicAdd(&acc[7 + v], (double)(fred[0] + fred[1] + fred[2] + fred[3]));
}

// -------- final: derive ||G||_F^2 from raw S, combine everything --------
__global__ __launch_bounds__(64) void k_final(
    const double* __restrict__ acc, const float* __restrict__ S,
    float* __restrict__ out) {
  __shared__ float t[2][32];
  int lane = threadIdx.x;
  #pragma unroll
  for (int zi = 0; zi < 2; ++zi) {
    if (lane < 32) {
      float tp = 0.f;
      for (int bb = 0; bb < 32; ++bb) tp += S[zi * 1024 + lane * 32 + bb];
      t[zi][lane] = tp * (1.f / 32.f);
    }
  }
  __syncthreads();
  double total[2];
  #pragma unroll
  for (int zi = 0; zi < 2; ++zi) {
    float u = 0.f;
    for (int bb = 0; bb < 32; ++bb) u += t[zi][bb];
    u *= (1.f / 32.f);
    double s = 0.0;
    for (int e = lane; e < 1024; e += 64) {
      int p = e >> 5, q = e & 31;
      float G = S[zi * 1024 + e] - t[zi][p] - t[zi][q] + u;
      s += (double)G * (double)G;
    }
    for (int off = 32; off; off >>= 1) s += __shfl_down(s, off);
    total[zi] = s;
  }
  if (lane == 0) {
    double inv_g = acc[0] / (32.0 * 8192.0);
    double v = 0.5 * (acc[1] + acc[2]) / 8192.0;
    double c = (total[0] - acc[3] + total[1] - acc[4]) / (961.0 * 8192.0);
    double gloss = 25.0 * inv_g + 25.0 * v + c;
    double mfg = acc[7] / (32.0 * 20.0 * 512.0);
    double mfl = acc[8] / (32.0 * 4.0 * 512.0);
    double mgg = acc[9] / (32.0 * 20.0 * 512.0);
    double mgl = acc[10] / (32.0 * 4.0 * 512.0);
    double lloss = 25.0 * (0.5 * (mfg + mfl) + 0.5 * (mgg + mgl));
    out[0] = (float)(0.25 * gloss + 0.75 * lloss);
  }
}

extern "C" void kernel_launch(void* const* d_in, const int* in_sizes, int n_in,
                              void* d_out, int out_size, void* d_ws, size_t ws_size,
                              hipStream_t stream) {
  const float* zg  = (const float*)d_in[0];
  const float* zl  = (const float*)d_in[1];
  const float* zgf = (const float*)d_in[2];
  const float* zlf = (const float*)d_in[3];
  const float* gg  = (const float*)d_in[4];
  const float* glo = (const float*)d_in[5];

  char* ws = (char*)d_ws;
  double* acc = (double*)(ws + OFF_ACC);
  float* S  = (float*)(ws + OFF_S);
  float* ng = (float*)(ws + OFF_NG);
  float* nl = (float*)(ws + OFF_NL);
  unsigned long long* rowNN = (unsigned long long*)(ws + OFF_ROWNN);
  unsigned long long* colNN = (unsigned long long*)(ws + OFF_COLNN);
  unsigned short* Abf = (unsigned short*)(ws + OFF_ABF);
  unsigned short* Bbf = (unsigned short*)(ws + OFF_BBF);

  hipMemsetAsync(ws + OFF_ACC, 0, 16 * sizeof(double), stream);
  hipMemsetAsync(ws + OFF_ROWNN, 0xFF, (size_t)8 * BATCH * (LG + LL), stream);

  k_global_stats<<<DZ / 64, 64, 0, stream>>>(zg, zl, acc);
  k_gram<<<dim3(528, 2), 256, 0, stream>>>(zg, zl, S);

  if (ws_size >= WS_NEED) {
    k_prep<<<(BATCH * (LG + LL)) / 4, 256, 0, stream>>>(zgf, zlf, Abf, Bbf, ng, nl);
    k_feat_mfma<<<dim3(LG / 64, LL / 64, BATCH), 256, 0, stream>>>(Abf, Bbf, ng, nl, rowNN, colNN);
  } else {
    k_norms<<<BATCH * (LG + LL), 64, 0, stream>>>(zgf, zlf, ng, nl);
    k_feat_nn<<<dim3(LG / 64, LL / 128, BATCH), 256, 0, stream>>>(zgf, zlf, ng, nl, rowNN, colNN);
  }
  k_sel<<<dim3(BATCH, 4), 256, 0, stream>>>(zgf, zlf, gg, glo, rowNN, colNN, acc);
  k_final<<<1, 64, 0, stream>>>(acc, S, (float*)d_out);
}

// Round 4
// 184.420 us; speedup vs baseline: 1.7637x; 1.0495x over previous
//
#include <hip/hip_runtime.h>
#include <hip/hip_bf16.h>

#define BATCH 32
#define DZ    8192
#define LG    576
#define LL    256
#define CH    512

// ---- ws layout (byte offsets) ----
#define OFF_ACC    0                          // double[16] = 128 B
#define OFF_S      128                        // float[2*1024] raw Gram S (a,b)
#define OFF_NG     (OFF_S + 4*2048)           // float[BATCH*LG]
#define OFF_NL     (OFF_NG + 4*BATCH*LG)      // float[BATCH*LL]
#define OFF_ROWNN  (OFF_NL + 4*BATCH*LL)      // u64[BATCH*LG]
#define OFF_COLNN  (OFF_ROWNN + 8*BATCH*LG)   // u64[BATCH*LL]
#define OFF_ABF    (OFF_COLNN + 8*BATCH*LL)   // bf16 bits [BATCH*LG*CH]
#define OFF_BBF    (OFF_ABF + 2*BATCH*LG*CH)  // bf16 bits [BATCH*LL*CH]
#define WS_NEED    (OFF_BBF + 2*(size_t)BATCH*LL*CH)

// acc: 0 inv_global, 1 var_a, 2 var_b, 3 diag_a, 4 diag_b,
//      7 feat_g, 8 feat_l, 9 grid_g, 10 grid_l

typedef __attribute__((ext_vector_type(8))) short bf16x8;
typedef __attribute__((ext_vector_type(4))) float f32x4;

__device__ __forceinline__ unsigned short f2bf(float x) {
  union { __hip_bfloat16 h; unsigned short u; } cv;
  cv.h = __float2bfloat16(x);
  return cv.u;
}

// -------- global VICReg stats: inv mse, var hinge, diag(cov)^2 --------
__global__ __launch_bounds__(64) void k_global_stats(
    const float* __restrict__ za, const float* __restrict__ zb,
    double* __restrict__ acc) {
  int i = blockIdx.x * 64 + threadIdx.x;
  float sa = 0.f, qa = 0.f, sb = 0.f, qb = 0.f, si = 0.f;
  #pragma unroll 8
  for (int b = 0; b < BATCH; ++b) {
    float va = za[(size_t)b * DZ + i];
    float vb = zb[(size_t)b * DZ + i];
    sa += va; qa += va * va;
    sb += vb; qb += vb * vb;
    float d = va - vb; si += d * d;
  }
  float ssa = qa - sa * sa * (1.f / 32.f);   // centered SS = 31*var
  float ssb = qb - sb * sb * (1.f / 32.f);
  float ra = fmaxf(0.f, 1.f - sqrtf(ssa * (1.f / 31.f) + 1e-4f));
  float rb = fmaxf(0.f, 1.f - sqrtf(ssb * (1.f / 31.f) + 1e-4f));
  float v0 = si, v1 = ra, v2 = rb, v3 = ssa * ssa, v4 = ssb * ssb;
  for (int off = 32; off; off >>= 1) {
    v0 += __shfl_down(v0, off); v1 += __shfl_down(v1, off);
    v2 += __shfl_down(v2, off); v3 += __shfl_down(v3, off);
    v4 += __shfl_down(v4, off);
  }
  if (threadIdx.x == 0) {
    atomicAdd(&acc[0], (double)v0); atomicAdd(&acc[1], (double)v1);
    atomicAdd(&acc[2], (double)v2); atomicAdd(&acc[3], (double)v3);
    atomicAdd(&acc[4], (double)v4);
  }
}

// -------- raw sample Gram S = z z^T (32x32, symmetric) --------
__global__ __launch_bounds__(256) void k_gram(
    const float* __restrict__ za, const float* __restrict__ zb,
    float* __restrict__ S) {
  int e = blockIdx.x;                  // 0..527 upper-tri pair
  const float* z = blockIdx.y ? zb : za;
  float* Sz = S + blockIdx.y * 1024;
  int p = 0, rem = e;
  while (rem >= 32 - p) { rem -= 32 - p; ++p; }
  int q = p + rem;
  const float4* zp = (const float4*)(z + (size_t)p * DZ);
  const float4* zq = (const float4*)(z + (size_t)q * DZ);
  float s = 0.f;
  for (int i = threadIdx.x; i < DZ / 4; i += 256) {
    float4 a = zp[i], b = zq[i];
    s += a.x * b.x + a.y * b.y + a.z * b.z + a.w * b.w;
  }
  for (int off = 32; off; off >>= 1) s += __shfl_down(s, off);
  __shared__ float w4[4];
  int lane = threadIdx.x & 63, wv = threadIdx.x >> 6;
  if (lane == 0) w4[wv] = s;
  __syncthreads();
  if (threadIdx.x == 0) {
    float r = w4[0] + w4[1] + w4[2] + w4[3];
    Sz[p * 32 + q] = r;
    if (p != q) Sz[q * 32 + p] = r;
  }
}

// -------- prep: fp32 -> bf16 copies + fp32 row norms --------
__global__ __launch_bounds__(256) void k_prep(
    const float* __restrict__ zgf, const float* __restrict__ zlf,
    unsigned short* __restrict__ Abf, unsigned short* __restrict__ Bbf,
    float* __restrict__ ng, float* __restrict__ nl) {
  int row = blockIdx.x * 4 + (threadIdx.x >> 6);
  int lane = threadIdx.x & 63;
  const float* src; unsigned short* dst; float* nrm;
  if (row < BATCH * LG) {
    src = zgf + (size_t)row * CH; dst = Abf + (size_t)row * CH; nrm = ng + row;
  } else {
    int rr = row - BATCH * LG;
    src = zlf + (size_t)rr * CH; dst = Bbf + (size_t)rr * CH; nrm = nl + rr;
  }
  const float4* s4 = (const float4*)src;
  float4 v0 = s4[lane * 2], v1 = s4[lane * 2 + 1];
  float ss = v0.x * v0.x + v0.y * v0.y + v0.z * v0.z + v0.w * v0.w +
             v1.x * v1.x + v1.y * v1.y + v1.z * v1.z + v1.w * v1.w;
  union { unsigned short h[8]; uint4 u; } pk;
  pk.h[0] = f2bf(v0.x); pk.h[1] = f2bf(v0.y); pk.h[2] = f2bf(v0.z); pk.h[3] = f2bf(v0.w);
  pk.h[4] = f2bf(v1.x); pk.h[5] = f2bf(v1.y); pk.h[6] = f2bf(v1.z); pk.h[7] = f2bf(v1.w);
  *(uint4*)(dst + lane * 8) = pk.u;
  for (int off = 32; off; off >>= 1) ss += __shfl_down(ss, off);
  if (lane == 0) *nrm = ss;
}

// -------- feature-space cdist via bf16 MFMA + fused NN argmin --------
__global__ __launch_bounds__(256) void k_feat_mfma(
    const unsigned short* __restrict__ Abf, const unsigned short* __restrict__ Bbf,
    const float* __restrict__ ng, const float* __restrict__ nl,
    unsigned long long* __restrict__ rowNN, unsigned long long* __restrict__ colNN) {
  const int b = blockIdx.z;
  const int row0 = blockIdx.x * 64;
  const int col0 = blockIdx.y * 64;
  const int tid = threadIdx.x;
  const int wave = tid >> 6, lane = tid & 63;
  const int m16 = lane & 15, quad = lane >> 4;
  const int wm = wave >> 1, wn = wave & 1;

  __shared__ unsigned short As[64][72];
  __shared__ unsigned short Bs[64][72];

  const unsigned short* Ag = Abf + ((size_t)(b * LG + row0)) * CH;
  const unsigned short* Bg = Bbf + ((size_t)(b * LL + col0)) * CH;

  const int sr = tid >> 2;
  const int sq = tid & 3;

  f32x4 acc[2][2] = {};

  for (int k0 = 0; k0 < CH; k0 += 64) {
    uint4 a0 = *(const uint4*)(Ag + (size_t)sr * CH + k0 + sq * 16);
    uint4 a1 = *(const uint4*)(Ag + (size_t)sr * CH + k0 + sq * 16 + 8);
    uint4 b0 = *(const uint4*)(Bg + (size_t)sr * CH + k0 + sq * 16);
    uint4 b1 = *(const uint4*)(Bg + (size_t)sr * CH + k0 + sq * 16 + 8);
    __syncthreads();
    *(uint4*)&As[sr][sq * 16] = a0; *(uint4*)&As[sr][sq * 16 + 8] = a1;
    *(uint4*)&Bs[sr][sq * 16] = b0; *(uint4*)&Bs[sr][sq * 16 + 8] = b1;
    __syncthreads();
    #pragma unroll
    for (int kk = 0; kk < 64; kk += 32) {
      bf16x8 af0 = *(const bf16x8*)&As[wm * 32 + m16][kk + quad * 8];
      bf16x8 af1 = *(const bf16x8*)&As[wm * 32 + 16 + m16][kk + quad * 8];
      bf16x8 bf0 = *(const bf16x8*)&Bs[wn * 32 + m16][kk + quad * 8];
      bf16x8 bf1 = *(const bf16x8*)&Bs[wn * 32 + 16 + m16][kk + quad * 8];
      acc[0][0] = __builtin_amdgcn_mfma_f32_16x16x32_bf16(af0, bf0, acc[0][0], 0, 0, 0);
      acc[0][1] = __builtin_amdgcn_mfma_f32_16x16x32_bf16(af0, bf1, acc[0][1], 0, 0, 0);
      acc[1][0] = __builtin_amdgcn_mfma_f32_16x16x32_bf16(af1, bf0, acc[1][0], 0, 0, 0);
      acc[1][1] = __builtin_amdgcn_mfma_f32_16x16x32_bf16(af1, bf1, acc[1][1], 0, 0, 0);
    }
  }

  float na[2][4], nb[2];
  #pragma unroll
  for (int i = 0; i < 2; ++i)
    #pragma unroll
    for (int r = 0; r < 4; ++r)
      na[i][r] = ng[b * LG + row0 + wm * 32 + i * 16 + quad * 4 + r];
  #pragma unroll
  for (int j = 0; j < 2; ++j)
    nb[j] = nl[b * LL + col0 + wn * 32 + j * 16 + m16];

  #pragma unroll
  for (int i = 0; i < 2; ++i) {
    #pragma unroll
    for (int r = 0; r < 4; ++r) {
      float d0 = fmaxf(na[i][r] + nb[0] - 2.f * acc[i][0][r], 0.f);
      float d1 = fmaxf(na[i][r] + nb[1] - 2.f * acc[i][1][r], 0.f);
      unsigned c0 = (unsigned)(col0 + wn * 32 + m16);
      unsigned long long p0 = (((unsigned long long)__float_as_uint(d0)) << 32) | c0;
      unsigned long long p1 = (((unsigned long long)__float_as_uint(d1)) << 32) | (c0 + 16);
      unsigned long long p = p0 < p1 ? p0 : p1;
      #pragma unroll
      for (int s = 1; s < 16; s <<= 1) {
        unsigned long long q = __shfl_xor(p, s);
        p = q < p ? q : p;
      }
      if (m16 == 0)
        atomicMin(&rowNN[(size_t)b * LG + row0 + wm * 32 + i * 16 + quad * 4 + r], p);
    }
  }
  #pragma unroll
  for (int j = 0; j < 2; ++j) {
    unsigned long long p = ~0ull;
    #pragma unroll
    for (int i = 0; i < 2; ++i) {
      #pragma unroll
      for (int r = 0; r < 4; ++r) {
        float d = fmaxf(na[i][r] + nb[j] - 2.f * acc[i][j][r], 0.f);
        unsigned rg = (unsigned)(row0 + wm * 32 + i * 16 + quad * 4 + r);
        unsigned long long pr = (((unsigned long long)__float_as_uint(d)) << 32) | rg;
        p = pr < p ? pr : p;
      }
    }
    unsigned long long q = __shfl_xor(p, 16); p = q < p ? q : p;
    q = __shfl_xor(p, 32); p = q < p ? q : p;
    if (quad == 0)
      atomicMin(&colNN[(size_t)b * LL + col0 + wn * 32 + j * 16 + m16], p);
  }
}

// -------- FALLBACK (small ws): fp32 VALU cdist + NN --------
__global__ __launch_bounds__(64) void k_norms(
    const float* __restrict__ zgf, const float* __restrict__ zlf,
    float* __restrict__ ng, float* __restrict__ nl) {
  int r = blockIdx.x;
  const float* src; float* dst;
  if (r < BATCH * LG) { src = zgf + (size_t)r * CH; dst = ng + r; }
  else { int rr = r - BATCH * LG; src = zlf + (size_t)rr * CH; dst = nl + rr; }
  float s = 0.f;
  for (int j = threadIdx.x; j < CH; j += 64) { float v = src[j]; s += v * v; }
  for (int off = 32; off > 0; off >>= 1) s += __shfl_down(s, off);
  if (threadIdx.x == 0) *dst = s;
}

__global__ __launch_bounds__(256) void k_feat_nn(
    const float* __restrict__ zgf, const float* __restrict__ zlf,
    const float* __restrict__ ng, const float* __restrict__ nl,
    unsigned long long* __restrict__ rowNN, unsigned long long* __restrict__ colNN) {
  const int b = blockIdx.z;
  const int row0 = blockIdx.x * 64;
  const int col0 = blockIdx.y * 128;
  const int tid = threadIdx.x;
  const int tx = tid & 15, ty = tid >> 4;
  __shared__ float As[64][20];
  __shared__ float Bs[128][20];
  __shared__ float Ds[64][130];
  const float* Ag = zgf + ((size_t)b * LG + row0) * CH;
  const float* Bg = zlf + ((size_t)b * LL + col0) * CH;
  float acc[4][8];
  #pragma unroll
  for (int i = 0; i < 4; ++i)
    #pragma unroll
    for (int j = 0; j < 8; ++j) acc[i][j] = 0.f;
  const int ar = tid >> 2;
  const int ak = (tid & 3) * 4;
  for (int k0 = 0; k0 < CH; k0 += 16) {
    float4 av  = *(const float4*)(Ag + (size_t)ar * CH + k0 + ak);
    float4 bv0 = *(const float4*)(Bg + (size_t)ar * CH + k0 + ak);
    float4 bv1 = *(const float4*)(Bg + (size_t)(ar + 64) * CH + k0 + ak);
    __syncthreads();
    *(float4*)&As[ar][ak] = av;
    *(float4*)&Bs[ar][ak] = bv0;
    *(float4*)&Bs[ar + 64][ak] = bv1;
    __syncthreads();
    #pragma unroll
    for (int k = 0; k < 16; ++k) {
      float a0 = As[ty][k], a1 = As[ty + 16][k], a2 = As[ty + 32][k], a3 = As[ty + 48][k];
      float bv[8];
      #pragma unroll
      for (int j = 0; j < 8; ++j) bv[j] = Bs[tx + 16 * j][k];
      #pragma unroll
      for (int j = 0; j < 8; ++j) {
        acc[0][j] += a0 * bv[j]; acc[1][j] += a1 * bv[j];
        acc[2][j] += a2 * bv[j]; acc[3][j] += a3 * bv[j];
      }
    }
  }
  float ngr[4], nlc[8];
  #pragma unroll
  for (int i = 0; i < 4; ++i) ngr[i] = ng[b * LG + row0 + ty + 16 * i];
  #pragma unroll
  for (int j = 0; j < 8; ++j) nlc[j] = nl[b * LL + col0 + tx + 16 * j];
  #pragma unroll
  for (int i = 0; i < 4; ++i)
    #pragma unroll
    for (int j = 0; j < 8; ++j)
      Ds[ty + 16 * i][tx + 16 * j] = fmaxf(ngr[i] + nlc[j] - 2.f * acc[i][j], 0.f);
  __syncthreads();
  if (tid < 64) {
    unsigned long long best = ~0ull;
    for (int c = 0; c < 128; ++c) {
      unsigned long long p =
          ((unsigned long long)__float_as_uint(Ds[tid][c]) << 32) | (unsigned)(col0 + c);
      best = p < best ? p : best;
    }
    atomicMin(&rowNN[(size_t)b * LG + row0 + tid], best);
  } else if (tid < 192) {
    int c = tid - 64;
    unsigned long long best = ~0ull;
    for (int r = 0; r < 64; ++r) {
      unsigned long long p =
          ((unsigned long long)__float_as_uint(Ds[r][c]) << 32) | (unsigned)(row0 + r);
      best = p < best ? p : best;
    }
    atomicMin(&colNN[(size_t)b * LL + col0 + c], best);
  }
}

// -------- selection: compile-time specialized per direction --------
struct SelSmem {
  unsigned long long keys[LG];
  unsigned int nnm[LG];
  float cxy[2 * LG];
  unsigned int plist[40];
  unsigned int cnt;
  float fred[4];
};

template <int V>
__device__ __forceinline__ void sel_case(
    SelSmem& sm, int b,
    const float* __restrict__ zgf, const float* __restrict__ zlf,
    const float* __restrict__ gg, const float* __restrict__ gl,
    const unsigned long long* __restrict__ rowNN,
    const unsigned long long* __restrict__ colNN,
    double* __restrict__ acc) {
  constexpr bool GDIR = (V == 0 || V == 2);
  constexpr int L1 = GDIR ? LG : LL;
  constexpr int L2 = GDIR ? LL : LG;
  constexpr int M  = GDIR ? 20 : 4;
  constexpr int NR = (L1 + 255) / 256;      // rows per thread (3 or 1)
  const float* fin  = GDIR ? zgf + (size_t)b * LG * CH : zlf + (size_t)b * LL * CH;
  const float* fcan = GDIR ? zlf + (size_t)b * LL * CH : zgf + (size_t)b * LG * CH;
  int tid = threadIdx.x, lane = tid & 63, wv = tid >> 6;
  if (tid == 0) sm.cnt = 0;

  if constexpr (V < 2) {
    const unsigned long long* src =
        (V == 0) ? rowNN + (size_t)b * LG : colNN + (size_t)b * LL;
    #pragma unroll
    for (int s = 0; s < NR; ++s) {
      int l = tid + s * 256;
      if (l < L1) {
        unsigned long long p = src[l];
        sm.keys[l] = (p & 0xFFFFFFFF00000000ull) | (unsigned)l;
        sm.nnm[l] = (unsigned)(p & 0xFFFFFFFFu);
      }
    }
  } else {
    const float* gin  = (V == 2) ? gg + (size_t)b * LG * 2 : gl + (size_t)b * LL * 2;
    const float* gcan = (V == 2) ? gl + (size_t)b * LL * 2 : gg + (size_t)b * LG * 2;
    #pragma unroll
    for (int s = 0; s < (2 * L2 + 255) / 256; ++s) {
      int i = tid + s * 256;
      if (i < 2 * L2) sm.cxy[i] = gcan[i];
    }
    __syncthreads();
    float x[NR], y[NR], bd[NR];
    unsigned bi[NR];
    #pragma unroll
    for (int s = 0; s < NR; ++s) {
      int l = tid + s * 256;
      x[s] = (l < L1) ? gin[2 * l] : 0.f;
      y[s] = (l < L1) ? gin[2 * l + 1] : 0.f;
      bd[s] = 3.4e38f; bi[s] = 0;
    }
    const float2* c2 = (const float2*)sm.cxy;
    #pragma unroll 8
    for (int m2 = 0; m2 < L2; ++m2) {      // strict <, ascending m2 = first-min (argmin)
      float2 c = c2[m2];
      #pragma unroll
      for (int s = 0; s < NR; ++s) {
        float dx = x[s] - c.x, dy = y[s] - c.y;
        float d2 = dx * dx + dy * dy;
        if (d2 < bd[s]) { bd[s] = d2; bi[s] = (unsigned)m2; }
      }
    }
    #pragma unroll
    for (int s = 0; s < NR; ++s) {
      int l = tid + s * 256;
      if (l < L1) {
        sm.keys[l] = ((unsigned long long)__float_as_uint(bd[s]) << 32) | (unsigned)l;
        sm.nnm[l] = bi[s];
      }
    }
  }
  __syncthreads();

  // rank count: key selected iff #{smaller keys} < M (keys distinct by low bits)
  unsigned long long myk[NR];
  int rk[NR];
  #pragma unroll
  for (int s = 0; s < NR; ++s) {
    int l = tid + s * 256;
    myk[s] = (l < L1) ? sm.keys[l] : ~0ull;
    rk[s] = 0;
  }
  #pragma unroll 8
  for (int j = 0; j < L1; ++j) {
    unsigned long long kj = sm.keys[j];    // wave-broadcast LDS read
    #pragma unroll
    for (int s = 0; s < NR; ++s) rk[s] += (kj < myk[s]) ? 1 : 0;
  }
  #pragma unroll
  for (int s = 0; s < NR; ++s) {
    int l = tid + s * 256;
    if (l < L1 && rk[s] < M) {
      unsigned slot = atomicAdd(&sm.cnt, 1u);
      sm.plist[2 * slot] = (unsigned)l;
      sm.plist[2 * slot + 1] = sm.nnm[l];
    }
  }
  __syncthreads();

  float part = 0.f;
  #pragma unroll 4
  for (int r = 0; r < M; ++r) {
    const float* a = fin  + (size_t)sm.plist[2 * r] * CH;
    const float* c = fcan + (size_t)sm.plist[2 * r + 1] * CH;
    #pragma unroll
    for (int jj = 0; jj < CH / 256; ++jj) {
      int j = tid + jj * 256;
      float d = a[j] - c[j];
      part += d * d;
    }
  }
  for (int s = 32; s; s >>= 1) part += __shfl_down(part, s);
  if (lane == 0) sm.fred[wv] = part;
  __syncthreads();
  if (tid == 0)
    atomicAdd(&acc[7 + V], (double)(sm.fred[0] + sm.fred[1] + sm.fred[2] + sm.fred[3]));
}

__global__ __launch_bounds__(256) void k_sel(
    const float* __restrict__ zgf, const float* __restrict__ zlf,
    const float* __restrict__ gg, const float* __restrict__ gl,
    const unsigned long long* __restrict__ rowNN,
    const unsigned long long* __restrict__ colNN,
    double* __restrict__ acc) {
  __shared__ SelSmem sm;
  int b = blockIdx.x;
  switch (blockIdx.y) {   // uniform branch; each case fully compile-time specialized
    case 0: sel_case<0>(sm, b, zgf, zlf, gg, gl, rowNN, colNN, acc); break;
    case 1: sel_case<1>(sm, b, zgf, zlf, gg, gl, rowNN, colNN, acc); break;
    case 2: sel_case<2>(sm, b, zgf, zlf, gg, gl, rowNN, colNN, acc); break;
    default: sel_case<3>(sm, b, zgf, zlf, gg, gl, rowNN, colNN, acc); break;
  }
}

// -------- final: derive ||G||_F^2 from raw S, combine everything --------
__global__ __launch_bounds__(64) void k_final(
    const double* __restrict__ acc, const float* __restrict__ S,
    float* __restrict__ out) {
  __shared__ float t[2][32];
  int lane = threadIdx.x;
  #pragma unroll
  for (int zi = 0; zi < 2; ++zi) {
    if (lane < 32) {
      float tp = 0.f;
      for (int bb = 0; bb < 32; ++bb) tp += S[zi * 1024 + lane * 32 + bb];
      t[zi][lane] = tp * (1.f / 32.f);
    }
  }
  __syncthreads();
  double total[2];
  #pragma unroll
  for (int zi = 0; zi < 2; ++zi) {
    float u = 0.f;
    for (int bb = 0; bb < 32; ++bb) u += t[zi][bb];
    u *= (1.f / 32.f);
    double s = 0.0;
    for (int e = lane; e < 1024; e += 64) {
      int p = e >> 5, q = e & 31;
      float G = S[zi * 1024 + e] - t[zi][p] - t[zi][q] + u;
      s += (double)G * (double)G;
    }
    for (int off = 32; off; off >>= 1) s += __shfl_down(s, off);
    total[zi] = s;
  }
  if (lane == 0) {
    double inv_g = acc[0] / (32.0 * 8192.0);
    double v = 0.5 * (acc[1] + acc[2]) / 8192.0;
    double c = (total[0] - acc[3] + total[1] - acc[4]) / (961.0 * 8192.0);
    double gloss = 25.0 * inv_g + 25.0 * v + c;
    double mfg = acc[7] / (32.0 * 20.0 * 512.0);
    double mfl = acc[8] / (32.0 * 4.0 * 512.0);
    double mgg = acc[9] / (32.0 * 20.0 * 512.0);
    double mgl = acc[10] / (32.0 * 4.0 * 512.0);
    double lloss = 25.0 * (0.5 * (mfg + mfl) + 0.5 * (mgg + mgl));
    out[0] = (float)(0.25 * gloss + 0.75 * lloss);
  }
}

extern "C" void kernel_launch(void* const* d_in, const int* in_sizes, int n_in,
                              void* d_out, int out_size, void* d_ws, size_t ws_size,
                              hipStream_t stream) {
  const float* zg  = (const float*)d_in[0];
  const float* zl  = (const float*)d_in[1];
  const float* zgf = (const float*)d_in[2];
  const float* zlf = (const float*)d_in[3];
  const float* gg  = (const float*)d_in[4];
  const float* glo = (const float*)d_in[5];

  char* ws = (char*)d_ws;
  double* acc = (double*)(ws + OFF_ACC);
  float* S  = (float*)(ws + OFF_S);
  float* ng = (float*)(ws + OFF_NG);
  float* nl = (float*)(ws + OFF_NL);
  unsigned long long* rowNN = (unsigned long long*)(ws + OFF_ROWNN);
  unsigned long long* colNN = (unsigned long long*)(ws + OFF_COLNN);
  unsigned short* Abf = (unsigned short*)(ws + OFF_ABF);
  unsigned short* Bbf = (unsigned short*)(ws + OFF_BBF);

  hipMemsetAsync(ws + OFF_ACC, 0, 16 * sizeof(double), stream);
  hipMemsetAsync(ws + OFF_ROWNN, 0xFF, (size_t)8 * BATCH * (LG + LL), stream);

  k_global_stats<<<DZ / 64, 64, 0, stream>>>(zg, zl, acc);
  k_gram<<<dim3(528, 2), 256, 0, stream>>>(zg, zl, S);

  if (ws_size >= WS_NEED) {
    k_prep<<<(BATCH * (LG + LL)) / 4, 256, 0, stream>>>(zgf, zlf, Abf, Bbf, ng, nl);
    k_feat_mfma<<<dim3(LG / 64, LL / 64, BATCH), 256, 0, stream>>>(Abf, Bbf, ng, nl, rowNN, colNN);
  } else {
    k_norms<<<BATCH * (LG + LL), 64, 0, stream>>>(zgf, zlf, ng, nl);
    k_feat_nn<<<dim3(LG / 64, LL / 128, BATCH), 256, 0, stream>>>(zgf, zlf, ng, nl, rowNN, colNN);
  }
  k_sel<<<dim3(BATCH, 4), 256, 0, stream>>>(zgf, zlf, gg, glo, rowNN, colNN, acc);
  k_final<<<1, 64, 0, stream>>>(acc, S, (float*)d_out);
}

// Round 5
// 169.350 us; speedup vs baseline: 1.9207x; 1.0890x over previous
//
#include <hip/hip_runtime.h>
#include <hip/hip_bf16.h>

#define BATCH 32
#define DZ    8192
#define LG    576
#define LL    256
#define CH    512

// ---- ws layout (byte offsets) ----
#define OFF_S      0                          // float[2*1024] raw Gram S
#define OFF_BSUM   8192                       // double[32*5] per-block stats
#define OFF_SELSUM 9472                       // double[4*32] per-(v,b) mse sums
#define OFF_NG     10496                      // float[BATCH*LG]
#define OFF_NL     84224                      // float[BATCH*LL]
#define OFF_ROWNN  116992                     // u64[BATCH*LG]
#define OFF_COLNN  264448                     // u64[BATCH*LL]   (contiguous w/ ROWNN)
#define OFF_ABF    329984                     // bf16 bits [BATCH*LG*CH]
#define OFF_BBF    19204352                   // bf16 bits [BATCH*LL*CH]
#define WS_NEED    27592960

typedef __attribute__((ext_vector_type(8))) short bf16x8;
typedef __attribute__((ext_vector_type(4))) float f32x4;

__device__ __forceinline__ unsigned short f2bf(float x) {
  union { __hip_bfloat16 h; unsigned short u; } cv;
  cv.h = __float2bfloat16(x);
  return cv.u;
}

// -------- fused: [blk<32] per-feature stats -> bsum ; [blk>=32] raw Gram S ----
__global__ __launch_bounds__(256) void k_stats_gram(
    const float* __restrict__ za, const float* __restrict__ zb,
    double* __restrict__ bsum, float* __restrict__ S) {
  __shared__ float sred[4][5];
  int tid = threadIdx.x, lane = tid & 63, wv = tid >> 6;
  int blk = blockIdx.x;
  if (blk < 32) {
    int i = blk * 256 + tid;                  // feature 0..8191
    float sa = 0.f, qa = 0.f, sb = 0.f, qb = 0.f, si = 0.f;
    #pragma unroll 8
    for (int b = 0; b < BATCH; ++b) {
      float va = za[(size_t)b * DZ + i];
      float vb = zb[(size_t)b * DZ + i];
      sa += va; qa += va * va;
      sb += vb; qb += vb * vb;
      float d = va - vb; si += d * d;
    }
    float ssa = qa - sa * sa * (1.f / 32.f);  // centered SS = 31*var
    float ssb = qb - sb * sb * (1.f / 32.f);
    float v0 = si;
    float v1 = fmaxf(0.f, 1.f - sqrtf(ssa * (1.f / 31.f) + 1e-4f));
    float v2 = fmaxf(0.f, 1.f - sqrtf(ssb * (1.f / 31.f) + 1e-4f));
    float v3 = ssa * ssa, v4 = ssb * ssb;
    for (int off = 32; off; off >>= 1) {
      v0 += __shfl_down(v0, off); v1 += __shfl_down(v1, off);
      v2 += __shfl_down(v2, off); v3 += __shfl_down(v3, off);
      v4 += __shfl_down(v4, off);
    }
    if (lane == 0) {
      sred[wv][0] = v0; sred[wv][1] = v1; sred[wv][2] = v2;
      sred[wv][3] = v3; sred[wv][4] = v4;
    }
    __syncthreads();
    if (tid < 5)
      bsum[blk * 5 + tid] =
          (double)(sred[0][tid] + sred[1][tid] + sred[2][tid] + sred[3][tid]);
  } else {
    int e = blk - 32;                         // 0..1055
    int zi = e >= 528; if (zi) e -= 528;
    const float* z = zi ? zb : za;
    float* Sz = S + zi * 1024;
    int p = 0, rem = e;
    while (rem >= 32 - p) { rem -= 32 - p; ++p; }
    int q = p + rem;
    const float4* zp = (const float4*)(z + (size_t)p * DZ);
    const float4* zq = (const float4*)(z + (size_t)q * DZ);
    float s = 0.f;
    #pragma unroll
    for (int ii = 0; ii < 8; ++ii) {
      int i = tid + ii * 256;
      float4 a = zp[i], b = zq[i];
      s += a.x * b.x + a.y * b.y + a.z * b.z + a.w * b.w;
    }
    for (int off = 32; off; off >>= 1) s += __shfl_down(s, off);
    if (lane == 0) sred[wv][0] = s;
    __syncthreads();
    if (tid == 0) {
      float r = sred[0][0] + sred[1][0] + sred[2][0] + sred[3][0];
      Sz[p * 32 + q] = r;
      if (p != q) Sz[q * 32 + p] = r;
    }
  }
}

// -------- prep: fp32 -> bf16 + row norms + NN-array init (no memset needed) ----
__global__ __launch_bounds__(256) void k_prep(
    const float* __restrict__ zgf, const float* __restrict__ zlf,
    unsigned short* __restrict__ Abf, unsigned short* __restrict__ Bbf,
    float* __restrict__ ng, float* __restrict__ nl,
    unsigned long long* __restrict__ nnInit) {
  int row = blockIdx.x * 4 + (threadIdx.x >> 6);
  int lane = threadIdx.x & 63;
  if (lane == 0) nnInit[row] = ~0ull;        // rowNN/colNN contiguous, 1:1 rows
  const float* src; unsigned short* dst; float* nrm;
  if (row < BATCH * LG) {
    src = zgf + (size_t)row * CH; dst = Abf + (size_t)row * CH; nrm = ng + row;
  } else {
    int rr = row - BATCH * LG;
    src = zlf + (size_t)rr * CH; dst = Bbf + (size_t)rr * CH; nrm = nl + rr;
  }
  const float4* s4 = (const float4*)src;
  float4 v0 = s4[lane * 2], v1 = s4[lane * 2 + 1];
  float ss = v0.x * v0.x + v0.y * v0.y + v0.z * v0.z + v0.w * v0.w +
             v1.x * v1.x + v1.y * v1.y + v1.z * v1.z + v1.w * v1.w;
  union { unsigned short h[8]; uint4 u; } pk;
  pk.h[0] = f2bf(v0.x); pk.h[1] = f2bf(v0.y); pk.h[2] = f2bf(v0.z); pk.h[3] = f2bf(v0.w);
  pk.h[4] = f2bf(v1.x); pk.h[5] = f2bf(v1.y); pk.h[6] = f2bf(v1.z); pk.h[7] = f2bf(v1.w);
  *(uint4*)(dst + lane * 8) = pk.u;
  for (int off = 32; off; off >>= 1) ss += __shfl_down(ss, off);
  if (lane == 0) *nrm = ss;
}

// -------- feature-space cdist via bf16 MFMA + fused NN argmin --------
__global__ __launch_bounds__(256) void k_feat_mfma(
    const unsigned short* __restrict__ Abf, const unsigned short* __restrict__ Bbf,
    const float* __restrict__ ng, const float* __restrict__ nl,
    unsigned long long* __restrict__ rowNN, unsigned long long* __restrict__ colNN) {
  const int b = blockIdx.z;
  const int row0 = blockIdx.x * 64;
  const int col0 = blockIdx.y * 64;
  const int tid = threadIdx.x;
  const int wave = tid >> 6, lane = tid & 63;
  const int m16 = lane & 15, quad = lane >> 4;
  const int wm = wave >> 1, wn = wave & 1;

  __shared__ unsigned short As[64][72];
  __shared__ unsigned short Bs[64][72];

  const unsigned short* Ag = Abf + ((size_t)(b * LG + row0)) * CH;
  const unsigned short* Bg = Bbf + ((size_t)(b * LL + col0)) * CH;

  const int sr = tid >> 2;
  const int sq = tid & 3;

  f32x4 acc[2][2] = {};

  for (int k0 = 0; k0 < CH; k0 += 64) {
    uint4 a0 = *(const uint4*)(Ag + (size_t)sr * CH + k0 + sq * 16);
    uint4 a1 = *(const uint4*)(Ag + (size_t)sr * CH + k0 + sq * 16 + 8);
    uint4 b0 = *(const uint4*)(Bg + (size_t)sr * CH + k0 + sq * 16);
    uint4 b1 = *(const uint4*)(Bg + (size_t)sr * CH + k0 + sq * 16 + 8);
    __syncthreads();
    *(uint4*)&As[sr][sq * 16] = a0; *(uint4*)&As[sr][sq * 16 + 8] = a1;
    *(uint4*)&Bs[sr][sq * 16] = b0; *(uint4*)&Bs[sr][sq * 16 + 8] = b1;
    __syncthreads();
    #pragma unroll
    for (int kk = 0; kk < 64; kk += 32) {
      bf16x8 af0 = *(const bf16x8*)&As[wm * 32 + m16][kk + quad * 8];
      bf16x8 af1 = *(const bf16x8*)&As[wm * 32 + 16 + m16][kk + quad * 8];
      bf16x8 bf0 = *(const bf16x8*)&Bs[wn * 32 + m16][kk + quad * 8];
      bf16x8 bf1 = *(const bf16x8*)&Bs[wn * 32 + 16 + m16][kk + quad * 8];
      acc[0][0] = __builtin_amdgcn_mfma_f32_16x16x32_bf16(af0, bf0, acc[0][0], 0, 0, 0);
      acc[0][1] = __builtin_amdgcn_mfma_f32_16x16x32_bf16(af0, bf1, acc[0][1], 0, 0, 0);
      acc[1][0] = __builtin_amdgcn_mfma_f32_16x16x32_bf16(af1, bf0, acc[1][0], 0, 0, 0);
      acc[1][1] = __builtin_amdgcn_mfma_f32_16x16x32_bf16(af1, bf1, acc[1][1], 0, 0, 0);
    }
  }

  float na[2][4], nb[2];
  #pragma unroll
  for (int i = 0; i < 2; ++i)
    #pragma unroll
    for (int r = 0; r < 4; ++r)
      na[i][r] = ng[b * LG + row0 + wm * 32 + i * 16 + quad * 4 + r];
  #pragma unroll
  for (int j = 0; j < 2; ++j)
    nb[j] = nl[b * LL + col0 + wn * 32 + j * 16 + m16];

  #pragma unroll
  for (int i = 0; i < 2; ++i) {
    #pragma unroll
    for (int r = 0; r < 4; ++r) {
      float d0 = fmaxf(na[i][r] + nb[0] - 2.f * acc[i][0][r], 0.f);
      float d1 = fmaxf(na[i][r] + nb[1] - 2.f * acc[i][1][r], 0.f);
      unsigned c0 = (unsigned)(col0 + wn * 32 + m16);
      unsigned long long p0 = (((unsigned long long)__float_as_uint(d0)) << 32) | c0;
      unsigned long long p1 = (((unsigned long long)__float_as_uint(d1)) << 32) | (c0 + 16);
      unsigned long long p = p0 < p1 ? p0 : p1;
      #pragma unroll
      for (int s = 1; s < 16; s <<= 1) {
        unsigned long long q = __shfl_xor(p, s);
        p = q < p ? q : p;
      }
      if (m16 == 0)
        atomicMin(&rowNN[(size_t)b * LG + row0 + wm * 32 + i * 16 + quad * 4 + r], p);
    }
  }
  #pragma unroll
  for (int j = 0; j < 2; ++j) {
    unsigned long long p = ~0ull;
    #pragma unroll
    for (int i = 0; i < 2; ++i) {
      #pragma unroll
      for (int r = 0; r < 4; ++r) {
        float d = fmaxf(na[i][r] + nb[j] - 2.f * acc[i][j][r], 0.f);
        unsigned rg = (unsigned)(row0 + wm * 32 + i * 16 + quad * 4 + r);
        unsigned long long pr = (((unsigned long long)__float_as_uint(d)) << 32) | rg;
        p = pr < p ? pr : p;
      }
    }
    unsigned long long q = __shfl_xor(p, 16); p = q < p ? q : p;
    q = __shfl_xor(p, 32); p = q < p ? q : p;
    if (quad == 0)
      atomicMin(&colNN[(size_t)b * LL + col0 + wn * 32 + j * 16 + m16], p);
  }
}

// -------- FALLBACK (small ws): fp32 VALU cdist + NN --------
__global__ __launch_bounds__(64) void k_norms(
    const float* __restrict__ zgf, const float* __restrict__ zlf,
    float* __restrict__ ng, float* __restrict__ nl,
    unsigned long long* __restrict__ nnInit) {
  int r = blockIdx.x;
  if (threadIdx.x == 0) nnInit[r] = ~0ull;
  const float* src; float* dst;
  if (r < BATCH * LG) { src = zgf + (size_t)r * CH; dst = ng + r; }
  else { int rr = r - BATCH * LG; src = zlf + (size_t)rr * CH; dst = nl + rr; }
  float s = 0.f;
  for (int j = threadIdx.x; j < CH; j += 64) { float v = src[j]; s += v * v; }
  for (int off = 32; off > 0; off >>= 1) s += __shfl_down(s, off);
  if (threadIdx.x == 0) *dst = s;
}

__global__ __launch_bounds__(256) void k_feat_nn(
    const float* __restrict__ zgf, const float* __restrict__ zlf,
    const float* __restrict__ ng, const float* __restrict__ nl,
    unsigned long long* __restrict__ rowNN, unsigned long long* __restrict__ colNN) {
  const int b = blockIdx.z;
  const int row0 = blockIdx.x * 64;
  const int col0 = blockIdx.y * 128;
  const int tid = threadIdx.x;
  const int tx = tid & 15, ty = tid >> 4;
  __shared__ float As[64][20];
  __shared__ float Bs[128][20];
  __shared__ float Ds[64][130];
  const float* Ag = zgf + ((size_t)b * LG + row0) * CH;
  const float* Bg = zlf + ((size_t)b * LL + col0) * CH;
  float acc[4][8];
  #pragma unroll
  for (int i = 0; i < 4; ++i)
    #pragma unroll
    for (int j = 0; j < 8; ++j) acc[i][j] = 0.f;
  const int ar = tid >> 2;
  const int ak = (tid & 3) * 4;
  for (int k0 = 0; k0 < CH; k0 += 16) {
    float4 av  = *(const float4*)(Ag + (size_t)ar * CH + k0 + ak);
    float4 bv0 = *(const float4*)(Bg + (size_t)ar * CH + k0 + ak);
    float4 bv1 = *(const float4*)(Bg + (size_t)(ar + 64) * CH + k0 + ak);
    __syncthreads();
    *(float4*)&As[ar][ak] = av;
    *(float4*)&Bs[ar][ak] = bv0;
    *(float4*)&Bs[ar + 64][ak] = bv1;
    __syncthreads();
    #pragma unroll
    for (int k = 0; k < 16; ++k) {
      float a0 = As[ty][k], a1 = As[ty + 16][k], a2 = As[ty + 32][k], a3 = As[ty + 48][k];
      float bv[8];
      #pragma unroll
      for (int j = 0; j < 8; ++j) bv[j] = Bs[tx + 16 * j][k];
      #pragma unroll
      for (int j = 0; j < 8; ++j) {
        acc[0][j] += a0 * bv[j]; acc[1][j] += a1 * bv[j];
        acc[2][j] += a2 * bv[j]; acc[3][j] += a3 * bv[j];
      }
    }
  }
  float ngr[4], nlc[8];
  #pragma unroll
  for (int i = 0; i < 4; ++i) ngr[i] = ng[b * LG + row0 + ty + 16 * i];
  #pragma unroll
  for (int j = 0; j < 8; ++j) nlc[j] = nl[b * LL + col0 + tx + 16 * j];
  #pragma unroll
  for (int i = 0; i < 4; ++i)
    #pragma unroll
    for (int j = 0; j < 8; ++j)
      Ds[ty + 16 * i][tx + 16 * j] = fmaxf(ngr[i] + nlc[j] - 2.f * acc[i][j], 0.f);
  __syncthreads();
  if (tid < 64) {
    unsigned long long best = ~0ull;
    for (int c = 0; c < 128; ++c) {
      unsigned long long p =
          ((unsigned long long)__float_as_uint(Ds[tid][c]) << 32) | (unsigned)(col0 + c);
      best = p < best ? p : best;
    }
    atomicMin(&rowNN[(size_t)b * LG + row0 + tid], best);
  } else if (tid < 192) {
    int c = tid - 64;
    unsigned long long best = ~0ull;
    for (int r = 0; r < 64; ++r) {
      unsigned long long p =
          ((unsigned long long)__float_as_uint(Ds[r][c]) << 32) | (unsigned)(row0 + r);
      best = p < best ? p : best;
    }
    atomicMin(&colNN[(size_t)b * LL + col0 + c], best);
  }
}

// -------- selection: compile-time specialized, explicit 8-wide ILP --------
struct SelSmem {
  unsigned long long keys[LG];
  unsigned int nnm[LG];
  float cxy[2 * LG];
  unsigned int plist[40];
  unsigned int cnt;
  float fred[4];
};

template <int V>
__device__ __forceinline__ void sel_case(
    SelSmem& sm, int b,
    const float* __restrict__ zgf, const float* __restrict__ zlf,
    const float* __restrict__ gg, const float* __restrict__ gl,
    const unsigned long long* __restrict__ rowNN,
    const unsigned long long* __restrict__ colNN,
    double* __restrict__ selsum) {
  constexpr bool GDIR = (V == 0 || V == 2);
  constexpr int L1 = GDIR ? LG : LL;
  constexpr int L2 = GDIR ? LL : LG;
  constexpr int M  = GDIR ? 20 : 4;
  constexpr int NR = (L1 + 255) / 256;
  const float* fin  = GDIR ? zgf + (size_t)b * LG * CH : zlf + (size_t)b * LL * CH;
  const float* fcan = GDIR ? zlf + (size_t)b * LL * CH : zgf + (size_t)b * LG * CH;
  int tid = threadIdx.x, lane = tid & 63, wv = tid >> 6;
  if (tid == 0) sm.cnt = 0;

  if constexpr (V < 2) {
    const unsigned long long* src =
        (V == 0) ? rowNN + (size_t)b * LG : colNN + (size_t)b * LL;
    #pragma unroll
    for (int s = 0; s < NR; ++s) {
      int l = tid + s * 256;
      if (l < L1) {
        unsigned long long p = src[l];
        sm.keys[l] = (p & 0xFFFFFFFF00000000ull) | (unsigned)l;
        sm.nnm[l] = (unsigned)(p & 0xFFFFFFFFu);
      }
    }
  } else {
    const float* gin  = (V == 2) ? gg + (size_t)b * LG * 2 : gl + (size_t)b * LL * 2;
    const float* gcan = (V == 2) ? gl + (size_t)b * LL * 2 : gg + (size_t)b * LG * 2;
    #pragma unroll
    for (int s = 0; s < (2 * L2 + 255) / 256; ++s) {
      int i = tid + s * 256;
      if (i < 2 * L2) sm.cxy[i] = gcan[i];
    }
    __syncthreads();
    float x[NR], y[NR], bd[NR];
    unsigned bi[NR];
    #pragma unroll
    for (int s = 0; s < NR; ++s) {
      int l = tid + s * 256;
      x[s] = (l < L1) ? gin[2 * l] : 0.f;
      y[s] = (l < L1) ? gin[2 * l + 1] : 0.f;
      bd[s] = 3.4e38f; bi[s] = 0;
    }
    const float2* c2 = (const float2*)sm.cxy;
    for (int m2 = 0; m2 < L2; m2 += 8) {
      float2 cc[8];                          // 8 LDS loads in flight
      #pragma unroll
      for (int u = 0; u < 8; ++u) cc[u] = c2[m2 + u];
      #pragma unroll
      for (int u = 0; u < 8; ++u)
        #pragma unroll
        for (int s = 0; s < NR; ++s) {
          float dx = x[s] - cc[u].x, dy = y[s] - cc[u].y;
          float d2 = dx * dx + dy * dy;
          if (d2 < bd[s]) { bd[s] = d2; bi[s] = (unsigned)(m2 + u); }  // first-min
        }
    }
    #pragma unroll
    for (int s = 0; s < NR; ++s) {
      int l = tid + s * 256;
      if (l < L1) {
        sm.keys[l] = ((unsigned long long)__float_as_uint(bd[s]) << 32) | (unsigned)l;
        sm.nnm[l] = bi[s];
      }
    }
  }
  __syncthreads();

  // rank count with 8-wide batched LDS reads
  unsigned long long myk[NR];
  int rk[NR];
  #pragma unroll
  for (int s = 0; s < NR; ++s) {
    int l = tid + s * 256;
    myk[s] = (l < L1) ? sm.keys[l] : ~0ull;
    rk[s] = 0;
  }
  for (int j = 0; j < L1; j += 8) {
    unsigned long long kk[8];
    #pragma unroll
    for (int u = 0; u < 8; ++u) kk[u] = sm.keys[j + u];
    #pragma unroll
    for (int u = 0; u < 8; ++u)
      #pragma unroll
      for (int s = 0; s < NR; ++s) rk[s] += (kk[u] < myk[s]) ? 1 : 0;
  }
  #pragma unroll
  for (int s = 0; s < NR; ++s) {
    int l = tid + s * 256;
    if (l < L1 && rk[s] < M) {
      unsigned slot = atomicAdd(&sm.cnt, 1u);
      sm.plist[2 * slot] = (unsigned)l;
      sm.plist[2 * slot + 1] = sm.nnm[l];
    }
  }
  __syncthreads();

  // MSE: wave-per-pair, fully unrolled float4 gathers
  float part = 0.f;
  #pragma unroll
  for (int rr = 0; rr < M / 4; ++rr) {
    int r = wv + rr * 4;
    const float4* a4 = (const float4*)(fin + (size_t)sm.plist[2 * r] * CH);
    const float4* c4 = (const float4*)(fcan + (size_t)sm.plist[2 * r + 1] * CH);
    float4 xa = a4[lane * 2], xb = a4[lane * 2 + 1];
    float4 ya = c4[lane * 2], yb = c4[lane * 2 + 1];
    float d0 = xa.x - ya.x, d1 = xa.y - ya.y, d2 = xa.z - ya.z, d3 = xa.w - ya.w;
    float d4 = xb.x - yb.x, d5 = xb.y - yb.y, d6 = xb.z - yb.z, d7 = xb.w - yb.w;
    part += d0 * d0 + d1 * d1 + d2 * d2 + d3 * d3 +
            d4 * d4 + d5 * d5 + d6 * d6 + d7 * d7;
  }
  for (int s = 32; s; s >>= 1) part += __shfl_down(part, s);
  if (lane == 0) sm.fred[wv] = part;
  __syncthreads();
  if (tid == 0)
    selsum[V * 32 + b] = (double)(sm.fred[0] + sm.fred[1] + sm.fred[2] + sm.fred[3]);
}

__global__ __launch_bounds__(256) void k_sel(
    const float* __restrict__ zgf, const float* __restrict__ zlf,
    const float* __restrict__ gg, const float* __restrict__ gl,
    const unsigned long long* __restrict__ rowNN,
    const unsigned long long* __restrict__ colNN,
    double* __restrict__ selsum) {
  __shared__ SelSmem sm;
  int b = blockIdx.x;
  switch (blockIdx.y) {
    case 0: sel_case<0>(sm, b, zgf, zlf, gg, gl, rowNN, colNN, selsum); break;
    case 1: sel_case<1>(sm, b, zgf, zlf, gg, gl, rowNN, colNN, selsum); break;
    case 2: sel_case<2>(sm, b, zgf, zlf, gg, gl, rowNN, colNN, selsum); break;
    default: sel_case<3>(sm, b, zgf, zlf, gg, gl, rowNN, colNN, selsum); break;
  }
}

// -------- final combine --------
__global__ __launch_bounds__(64) void k_final(
    const double* __restrict__ bsum, const double* __restrict__ selsum,
    const float* __restrict__ S, float* __restrict__ out) {
  __shared__ float t[2][32];
  __shared__ double sacc[5];
  __shared__ double smf[4];
  int lane = threadIdx.x;
  #pragma unroll
  for (int zi = 0; zi < 2; ++zi) {
    if (lane < 32) {
      float tp = 0.f;
      for (int bb = 0; bb < 32; ++bb) tp += S[zi * 1024 + lane * 32 + bb];
      t[zi][lane] = tp * (1.f / 32.f);
    }
  }
  if (lane < 5) {
    double s = 0.0;
    for (int blk = 0; blk < 32; ++blk) s += bsum[blk * 5 + lane];
    sacc[lane] = s;
  }
  if (lane >= 8 && lane < 12) {
    int v = lane - 8;
    double s = 0.0;
    for (int bb = 0; bb < 32; ++bb) s += selsum[v * 32 + bb];
    smf[v] = s;
  }
  __syncthreads();
  double total[2];
  #pragma unroll
  for (int zi = 0; zi < 2; ++zi) {
    float u = 0.f;
    for (int bb = 0; bb < 32; ++bb) u += t[zi][bb];
    u *= (1.f / 32.f);
    double s = 0.0;
    for (int e = lane; e < 1024; e += 64) {
      int p = e >> 5, q = e & 31;
      float G = S[zi * 1024 + e] - t[zi][p] - t[zi][q] + u;
      s += (double)G * (double)G;
    }
    for (int off = 32; off; off >>= 1) s += __shfl_down(s, off);
    total[zi] = s;
  }
  if (lane == 0) {
    double inv_g = sacc[0] / (32.0 * 8192.0);
    double v = 0.5 * (sacc[1] + sacc[2]) / 8192.0;
    double c = (total[0] - sacc[3] + total[1] - sacc[4]) / (961.0 * 8192.0);
    double gloss = 25.0 * inv_g + 25.0 * v + c;
    double mfg = smf[0] / (32.0 * 20.0 * 512.0);
    double mfl = smf[1] / (32.0 * 4.0 * 512.0);
    double mgg = smf[2] / (32.0 * 20.0 * 512.0);
    double mgl = smf[3] / (32.0 * 4.0 * 512.0);
    double lloss = 25.0 * (0.5 * (mfg + mfl) + 0.5 * (mgg + mgl));
    out[0] = (float)(0.25 * gloss + 0.75 * lloss);
  }
}

extern "C" void kernel_launch(void* const* d_in, const int* in_sizes, int n_in,
                              void* d_out, int out_size, void* d_ws, size_t ws_size,
                              hipStream_t stream) {
  const float* zg  = (const float*)d_in[0];
  const float* zl  = (const float*)d_in[1];
  const float* zgf = (const float*)d_in[2];
  const float* zlf = (const float*)d_in[3];
  const float* gg  = (const float*)d_in[4];
  const float* glo = (const float*)d_in[5];

  char* ws = (char*)d_ws;
  float* S       = (float*)(ws + OFF_S);
  double* bsum   = (double*)(ws + OFF_BSUM);
  double* selsum = (double*)(ws + OFF_SELSUM);
  float* ng = (float*)(ws + OFF_NG);
  float* nl = (float*)(ws + OFF_NL);
  unsigned long long* rowNN = (unsigned long long*)(ws + OFF_ROWNN);
  unsigned long long* colNN = (unsigned long long*)(ws + OFF_COLNN);
  unsigned short* Abf = (unsigned short*)(ws + OFF_ABF);
  unsigned short* Bbf = (unsigned short*)(ws + OFF_BBF);

  k_stats_gram<<<32 + 1056, 256, 0, stream>>>(zg, zl, bsum, S);

  if (ws_size >= WS_NEED) {
    k_prep<<<(BATCH * (LG + LL)) / 4, 256, 0, stream>>>(zgf, zlf, Abf, Bbf, ng, nl, rowNN);
    k_feat_mfma<<<dim3(LG / 64, LL / 64, BATCH), 256, 0, stream>>>(Abf, Bbf, ng, nl, rowNN, colNN);
  } else {
    k_norms<<<BATCH * (LG + LL), 64, 0, stream>>>(zgf, zlf, ng, nl, rowNN);
    k_feat_nn<<<dim3(LG / 64, LL / 128, BATCH), 256, 0, stream>>>(zgf, zlf, ng, nl, rowNN, colNN);
  }
  k_sel<<<dim3(BATCH, 4), 256, 0, stream>>>(zgf, zlf, gg, glo, rowNN, colNN, selsum);
  k_final<<<1, 64, 0, stream>>>(bsum, selsum, S, (float*)d_out);
}